// Round 6
// baseline (1372.649 us; speedup 1.0000x reference)
//
#include <hip/hip_runtime.h>
#include <cstdint>
#include <cstddef>

#define NN 50000
#define EE 800000
#define INF 512
#define HH  256
#define CC  10
#define NB2 391            // ceil(2*NN/256) scan blocks
#define NTB 782            // ceil(NN/64)  tail blocks
#define SPMM_BLOCKS 1568

using bfrag = __attribute__((ext_vector_type(8))) __bf16;
using f32x4 = __attribute__((ext_vector_type(4))) float;

__device__ inline unsigned short f2bf(float x) {
    unsigned u = __builtin_bit_cast(unsigned, x);
    unsigned r = u + 0x7FFFu + ((u >> 16) & 1u);
    return (unsigned short)(r >> 16);
}
__device__ inline float bf2f(unsigned short h) {
    return __builtin_bit_cast(float, (unsigned)h << 16);
}

// ---------------------------------------------------------------- weight casts
template<int K>
__global__ void k_cast_wt(const float* __restrict__ W, ushort* __restrict__ Wt) {
    int idx = blockIdx.x * blockDim.x + threadIdx.x;
    if (idx >= K * HH) return;
    int n = idx / K, k = idx % K;
    Wt[idx] = f2bf(W[(size_t)k * HH + n]);
}

__global__ void k_cast_wtail(const float* __restrict__ Wfc, const float* __restrict__ Wd,
                             ushort* __restrict__ Wt1) {
    int idx = blockIdx.x * blockDim.x + threadIdx.x;
    if (idx >= 16 * HH) return;
    int n = idx >> 8, k = idx & 255;
    float v = 0.f;
    if (n < 10)       v = Wfc[(size_t)k * 10 + n];
    else if (n < 12)  v = Wd[(size_t)(HH + k) * 2 + (n - 10)];
    Wt1[idx] = f2bf(v);
}

__global__ void k_cast_wtail2(const float* __restrict__ Wd, ushort* __restrict__ Wt2) {
    int idx = blockIdx.x * blockDim.x + threadIdx.x;
    if (idx >= 16 * HH) return;
    int n = idx >> 8, k = idx & 255;
    float v = (n < 2) ? Wd[(size_t)k * 2 + n] : 0.f;
    Wt2[idx] = f2bf(v);
}

// ---------------------------------------------------------------- degrees (both graphs)
// cnt layout: [out_s][in_s][out_t][in_t], each NN
__global__ void k_degrees2(const int* __restrict__ src_s, const int* __restrict__ dst_s,
                           const int* __restrict__ src_t, const int* __restrict__ dst_t,
                           int* __restrict__ cnt) {
    int e = blockIdx.x * blockDim.x + threadIdx.x;
    if (e < EE) {
        atomicAdd(&cnt[src_s[e]], 1);
        atomicAdd(&cnt[NN + dst_s[e]], 1);
    } else if (e < 2 * EE) {
        int e2 = e - EE;
        atomicAdd(&cnt[2 * NN + src_t[e2]], 1);
        atomicAdd(&cnt[3 * NN + dst_t[e2]], 1);
    }
}

// ------------------------------------------------- 3-phase scan over in-degrees (2NN)
// logical value i: i<NN -> cnt[NN+i] (in_s), else cnt[2NN+i] (in_t)
__global__ void k_scan_blk(const int* __restrict__ cnt, int* __restrict__ off,
                           int* __restrict__ btot) {
    __shared__ int wsum[4];
    int tid = threadIdx.x, lane = tid & 63, wid = tid >> 6;
    int i = blockIdx.x * 256 + tid;
    int v = 0;
    if (i < 2 * NN) v = (i < NN) ? cnt[NN + i] : cnt[2 * NN + i];
    int s = v;
    #pragma unroll
    for (int o = 1; o < 64; o <<= 1) {
        int t = __shfl_up(s, o, 64);
        if (lane >= o) s += t;
    }
    if (lane == 63) wsum[wid] = s;
    __syncthreads();
    if (tid == 0) {
        int a = 0;
        #pragma unroll
        for (int w2 = 0; w2 < 4; ++w2) { int t = wsum[w2]; wsum[w2] = a; a += t; }
        btot[blockIdx.x] = a;
    }
    __syncthreads();
    if (i < 2 * NN) off[i] = wsum[wid] + s - v;
}

__global__ void k_scan_tops(const int* __restrict__ btot, int* __restrict__ bbase,
                            int* __restrict__ off) {
    __shared__ int wsum[8];
    int tid = threadIdx.x, lane = tid & 63, wid = tid >> 6;
    int v = (tid < NB2) ? btot[tid] : 0;
    int s = v;
    #pragma unroll
    for (int o = 1; o < 64; o <<= 1) {
        int t = __shfl_up(s, o, 64);
        if (lane >= o) s += t;
    }
    if (lane == 63) wsum[wid] = s;
    __syncthreads();
    if (tid == 0) {
        int a = 0;
        #pragma unroll
        for (int w2 = 0; w2 < 8; ++w2) { int t = wsum[w2]; wsum[w2] = a; a += t; }
        off[2 * NN] = a;
    }
    __syncthreads();
    if (tid < NB2) bbase[tid] = wsum[wid] + s - v;
}

// fixup + norms (both graphs) + cur copy + zero spmm counters
__global__ void k_scan_fin(int* __restrict__ off, const int* __restrict__ bbase,
                           int* __restrict__ cur, const int* __restrict__ cnt,
                           float* __restrict__ ns, float* __restrict__ nd,
                           int* __restrict__ ctr) {
    if (blockIdx.x == 0 && threadIdx.x < 32) ctr[threadIdx.x] = 0;
    int i = blockIdx.x * blockDim.x + threadIdx.x;
    if (i >= 2 * NN) return;
    int o = off[i] + bbase[i >> 8];
    off[i] = o;
    cur[i] = o;
    int co = (i < NN) ? cnt[i] : cnt[NN + i];          // out-degree
    int ci = (i < NN) ? cnt[NN + i] : cnt[2 * NN + i]; // in-degree
    ns[i] = 1.0f / sqrtf(fmaxf((float)co, 1.0f));
    nd[i] = 1.0f / sqrtf(fmaxf((float)ci, 1.0f));
}

__global__ void k_fill2(const int* __restrict__ src_s, const int* __restrict__ dst_s,
                        const int* __restrict__ src_t, const int* __restrict__ dst_t,
                        int* __restrict__ cur, int* __restrict__ csr_src) {
    int e = blockIdx.x * blockDim.x + threadIdx.x;
    if (e < EE) {
        int p = atomicAdd(&cur[dst_s[e]], 1);
        csr_src[p] = src_s[e];
    } else if (e < 2 * EE) {
        int e2 = e - EE;
        int p = atomicAdd(&cur[NN + dst_t[e2]], 1);
        csr_src[p] = src_t[e2];
    }
}

// ---------------------------------------------------------------- MFMA GEMM
// BM=128, BN=256 (full width). y2 output in grouped layout [8][NN][32].
// y2[grp][row][c] = (A @ W)[row][grp*32+c] * ns[row]
template<int K, bool F32A>
__global__ __launch_bounds__(256, 2) void k_gemm(
        const void* __restrict__ Ap, const ushort* __restrict__ Bt,
        const float* __restrict__ ns, ushort* __restrict__ y2) {
    __shared__ ushort As[128 * 64];
    __shared__ ushort Bs[256 * 64];
    const int m0 = blockIdx.x * 128;
    const int t = threadIdx.x;
    const int wid = t >> 6, lane = t & 63;
    const int wr = (wid & 1) * 64;     // wave rows: 64
    const int wc = (wid >> 1) * 128;   // wave cols: 128
    const int l15 = lane & 15, lg = lane >> 4;

    f32x4 acc[4][8];
    #pragma unroll
    for (int m = 0; m < 4; ++m)
        #pragma unroll
        for (int n = 0; n < 8; ++n)
            acc[m][n] = {0.f, 0.f, 0.f, 0.f};

    const int srow = t >> 3;
    const int schunk = t & 7;

    for (int k0 = 0; k0 < K; k0 += 64) {
        #pragma unroll
        for (int i = 0; i < 4; ++i) {        // A tile 128x64
            int row = srow + i * 32;
            int sw = ((schunk ^ (row & 7)) * 8);
            int m = m0 + row; if (m >= NN) m = NN - 1;
            uint4 va;
            if constexpr (F32A) {
                const float* ap = (const float*)Ap + (size_t)m * K + k0 + schunk * 8;
                float4 f0 = *reinterpret_cast<const float4*>(ap);
                float4 f1 = *reinterpret_cast<const float4*>(ap + 4);
                va.x = (unsigned)f2bf(f0.x) | ((unsigned)f2bf(f0.y) << 16);
                va.y = (unsigned)f2bf(f0.z) | ((unsigned)f2bf(f0.w) << 16);
                va.z = (unsigned)f2bf(f1.x) | ((unsigned)f2bf(f1.y) << 16);
                va.w = (unsigned)f2bf(f1.z) | ((unsigned)f2bf(f1.w) << 16);
            } else {
                va = *reinterpret_cast<const uint4*>((const ushort*)Ap + (size_t)m * K + k0 + schunk * 8);
            }
            *reinterpret_cast<uint4*>(&As[row * 64 + sw]) = va;
        }
        #pragma unroll
        for (int i = 0; i < 8; ++i) {        // B tile 256x64
            int row = srow + i * 32;
            int sw = ((schunk ^ (row & 7)) * 8);
            uint4 vb = *reinterpret_cast<const uint4*>(&Bt[(size_t)row * K + k0 + schunk * 8]);
            *reinterpret_cast<uint4*>(&Bs[row * 64 + sw]) = vb;
        }
        __syncthreads();
        #pragma unroll
        for (int kk = 0; kk < 64; kk += 32) {
            const int kc = kk >> 3;
            bfrag af[4];
            #pragma unroll
            for (int m = 0; m < 4; ++m) {
                int row = wr + m * 16 + l15;
                af[m] = *reinterpret_cast<const bfrag*>(&As[row * 64 + (((lg + kc) ^ (row & 7)) * 8)]);
            }
            #pragma unroll
            for (int n = 0; n < 8; ++n) {
                int row = wc + n * 16 + l15;
                bfrag bg = *reinterpret_cast<const bfrag*>(&Bs[row * 64 + (((lg + kc) ^ (row & 7)) * 8)]);
                #pragma unroll
                for (int m = 0; m < 4; ++m)
                    acc[m][n] = __builtin_amdgcn_mfma_f32_16x16x32_bf16(af[m], bg, acc[m][n], 0, 0, 0);
            }
        }
        __syncthreads();
    }
    #pragma unroll
    for (int m = 0; m < 4; ++m) {
        #pragma unroll
        for (int r = 0; r < 4; ++r) {
            int row = m0 + wr + m * 16 + lg * 4 + r;
            if (row >= NN) continue;
            float nsv = ns[row];
            #pragma unroll
            for (int n = 0; n < 8; ++n) {
                int col = wc + n * 16 + l15;
                int grp = col >> 5, colw = col & 31;
                y2[(size_t)grp * NN * 32 + (size_t)row * 32 + colw] = f2bf(acc[m][n][r] * nsv);
            }
        }
    }
}

// ------------------------------------------------- SpMM, XCD-pinned work-stealing
// y2 grouped layout: group slice is contiguous 3.2MB -> L2-resident per XCD.
// Blocks read HW XCC_ID and drain their own group's chunk counter first.
__device__ inline void add8(float* a, uint4 v) {
    a[0] += __builtin_bit_cast(float, v.x << 16);
    a[1] += __builtin_bit_cast(float, v.x & 0xffff0000u);
    a[2] += __builtin_bit_cast(float, v.y << 16);
    a[3] += __builtin_bit_cast(float, v.y & 0xffff0000u);
    a[4] += __builtin_bit_cast(float, v.z << 16);
    a[5] += __builtin_bit_cast(float, v.z & 0xffff0000u);
    a[6] += __builtin_bit_cast(float, v.w << 16);
    a[7] += __builtin_bit_cast(float, v.w & 0xffff0000u);
}

__global__ __launch_bounds__(256) void k_spmm3(
        const ushort* __restrict__ y2, const int* __restrict__ off,
        const int* __restrict__ csr_src, const float* __restrict__ nd_arr,
        const float* __restrict__ bias, ushort* __restrict__ h_out,
        int* __restrict__ ctr) {
    // HW_REG_XCC_ID: id=20, offset=0, size=32 -> simm16 = 20 | (31<<11)
    int xcd = __builtin_amdgcn_s_getreg(20 | (31 << 11)) & 7;
    const int tid = threadIdx.x;
    const int lane = tid & 63, wid = tid >> 6;
    const int slot = wid * 16 + (lane >> 2);   // 0..63 node slot within chunk
    const int sub = lane & 3;                  // 16B sub-chunk of 32-col slice
    __shared__ int sh_chunk;

    for (int gi = 0; gi < 8; ++gi) {
        int grp = (xcd + gi) & 7;
        const ushort* ybase = y2 + (size_t)grp * NN * 32 + sub * 8;
        float bia[8];
        #pragma unroll
        for (int j = 0; j < 8; ++j) bia[j] = bias[grp * 32 + sub * 8 + j];
        while (true) {
            __syncthreads();
            if (tid == 0) sh_chunk = atomicAdd(&ctr[grp], 1);
            __syncthreads();
            int c = sh_chunk;
            if (c * 64 >= NN) break;
            int n = c * 64 + slot;
            if (n < NN) {
                int s0 = off[n], s1 = off[n + 1];
                float a[8] = {0.f, 0.f, 0.f, 0.f, 0.f, 0.f, 0.f, 0.f};
                for (int e = s0; e < s1; ++e) {
                    int s = csr_src[e];
                    uint4 v = *reinterpret_cast<const uint4*>(&ybase[(size_t)s * 32]);
                    add8(a, v);
                }
                float nd = nd_arr[n];
                ushort r[8];
                #pragma unroll
                for (int j = 0; j < 8; ++j) r[j] = f2bf(fmaxf(a[j] * nd + bia[j], 0.f));
                uint4 pk;
                pk.x = (unsigned)r[0] | ((unsigned)r[1] << 16);
                pk.y = (unsigned)r[2] | ((unsigned)r[3] << 16);
                pk.z = (unsigned)r[4] | ((unsigned)r[5] << 16);
                pk.w = (unsigned)r[6] | ((unsigned)r[7] << 16);
                *reinterpret_cast<uint4*>(&h_out[(size_t)n * 256 + grp * 32 + sub * 8]) = pk;
            }
        }
    }
}

// ------------------------------------------------- MFMA tail: fc + dlog + losses
__global__ __launch_bounds__(256) void k_tail_mfma(
        const ushort* __restrict__ h0, const ushort* __restrict__ h1,
        const ushort* __restrict__ Wt1, const ushort* __restrict__ Wt2,
        const float* __restrict__ bfc, const float* __restrict__ bd,
        const int* __restrict__ labels, int g,
        float* __restrict__ pcls, float* __restrict__ pdom) {
    __shared__ float sT1[4][16][17];
    __shared__ float sT2[4][16][17];
    __shared__ float sc[4], sd[4];
    const int tid = threadIdx.x;
    const int wid = tid >> 6, lane = tid & 63;
    const int l15 = lane & 15, lg = lane >> 4;
    const int base = blockIdx.x * 64 + wid * 16;

    int arow = base + l15; if (arow >= NN) arow = NN - 1;
    const ushort* a1 = h1 + (size_t)arow * 256 + lg * 8;
    const ushort* a0 = h0 + (size_t)arow * 256 + lg * 8;
    const ushort* b1 = Wt1 + (size_t)l15 * 256 + lg * 8;
    const ushort* b2 = Wt2 + (size_t)l15 * 256 + lg * 8;
    f32x4 acc1 = {0.f, 0.f, 0.f, 0.f};
    f32x4 acc2 = {0.f, 0.f, 0.f, 0.f};
    #pragma unroll
    for (int kk = 0; kk < 8; ++kk) {
        bfrag af1 = *reinterpret_cast<const bfrag*>(a1 + kk * 32);
        bfrag bg1 = *reinterpret_cast<const bfrag*>(b1 + kk * 32);
        acc1 = __builtin_amdgcn_mfma_f32_16x16x32_bf16(af1, bg1, acc1, 0, 0, 0);
        bfrag af0 = *reinterpret_cast<const bfrag*>(a0 + kk * 32);
        bfrag bg2 = *reinterpret_cast<const bfrag*>(b2 + kk * 32);
        acc2 = __builtin_amdgcn_mfma_f32_16x16x32_bf16(af0, bg2, acc2, 0, 0, 0);
    }
    #pragma unroll
    for (int j = 0; j < 4; ++j) {
        sT1[wid][lg * 4 + j][l15] = acc1[j];
        sT2[wid][lg * 4 + j][l15] = acc2[j];
    }
    __syncthreads();

    float cls = 0.f, dom = 0.f;
    int n = base + lane;
    if (lane < 16 && n < NN) {
        float lgt[10];
        #pragma unroll
        for (int c = 0; c < 10; ++c) lgt[c] = sT1[wid][lane][c] + bfc[c];
        float dl0 = bd[0] + sT2[wid][lane][0] + sT1[wid][lane][10];
        float dl1 = bd[1] + sT2[wid][lane][1] + sT1[wid][lane][11];
        if (g == 0) {
            float m = lgt[0];
            #pragma unroll
            for (int c = 1; c < 10; ++c) m = fmaxf(m, lgt[c]);
            float s = 0.f;
            #pragma unroll
            for (int c = 0; c < 10; ++c) s += expf(lgt[c] - m);
            int lab = labels[n];
            float tgt = lgt[0];
            #pragma unroll
            for (int c = 1; c < 10; ++c) tgt = (c == lab) ? lgt[c] : tgt;
            cls = -(tgt - (m + logf(s)));
        }
        float m2 = fmaxf(dl0, dl1);
        float lse2 = m2 + logf(expf(dl0 - m2) + expf(dl1 - m2));
        dom = -((g ? dl1 : dl0) - lse2);
    }
    #pragma unroll
    for (int o = 1; o < 16; o <<= 1) {
        cls += __shfl_xor(cls, o, 64);
        dom += __shfl_xor(dom, o, 64);
    }
    if (lane == 0) { sc[wid] = cls; sd[wid] = dom; }
    __syncthreads();
    if (tid == 0) {
        float c = sc[0] + sc[1] + sc[2] + sc[3];
        float d = sd[0] + sd[1] + sd[2] + sd[3];
        if (g == 0) pcls[blockIdx.x] = c;
        pdom[g * NTB + blockIdx.x] = d;
    }
}

__global__ void k_finalize(const float* __restrict__ pcls, const float* __restrict__ pdom,
                           float* __restrict__ out) {
    __shared__ float sc[4], sd[4];
    int tid = threadIdx.x, lane = tid & 63, wid = tid >> 6;
    float c = 0.f, d = 0.f;
    for (int i = tid; i < NTB; i += 256) c += pcls[i];
    for (int i = tid; i < 2 * NTB; i += 256) d += pdom[i];
    #pragma unroll
    for (int o = 32; o; o >>= 1) {
        c += __shfl_xor(c, o, 64);
        d += __shfl_xor(d, o, 64);
    }
    if (lane == 0) { sc[wid] = c; sd[wid] = d; }
    __syncthreads();
    if (tid == 0) {
        float ct = sc[0] + sc[1] + sc[2] + sc[3];
        float dt = sd[0] + sd[1] + sd[2] + sd[3];
        out[0] = ct / (float)NN + 0.01f * (dt / (float)(2 * NN));
    }
}

// ---------------------------------------------------------------- launch
extern "C" void kernel_launch(void* const* d_in, const int* in_sizes, int n_in,
                              void* d_out, int out_size, void* d_ws, size_t ws_size,
                              hipStream_t stream) {
    const float* features_s = (const float*)d_in[0];
    const int*   labels_s   = (const int*)d_in[1];
    const float* features_t = (const float*)d_in[2];
    const int*   src_s      = (const int*)d_in[3];
    const int*   dst_s      = (const int*)d_in[4];
    const int*   src_t      = (const int*)d_in[5];
    const int*   dst_t      = (const int*)d_in[6];
    const float* W0         = (const float*)d_in[7];
    const float* b0         = (const float*)d_in[8];
    const float* W1         = (const float*)d_in[9];
    const float* b1         = (const float*)d_in[10];
    const float* Wfc        = (const float*)d_in[11];
    const float* bfc        = (const float*)d_in[12];
    const float* Wd         = (const float*)d_in[13];
    const float* bd         = (const float*)d_in[14];
    float* out = (float*)d_out;

    auto align256 = [](size_t x) { return (x + 255) & ~(size_t)255; };
    char* w = (char*)d_ws;
    ushort* h0     = (ushort*)w; w += align256((size_t)NN * HH * 2);     // 25.6 MB
    ushort* h1     = (ushort*)w; w += align256((size_t)NN * HH * 2);     // 25.6 MB
    ushort* y2     = (ushort*)w; w += align256((size_t)NN * HH * 2);     // 25.6 MB grouped
    ushort* W0t    = (ushort*)w; w += align256((size_t)INF * HH * 2);
    ushort* W1t    = (ushort*)w; w += align256((size_t)HH * HH * 2);
    ushort* Wt1    = (ushort*)w; w += align256((size_t)16 * HH * 2);
    ushort* Wt2    = (ushort*)w; w += align256((size_t)16 * HH * 2);
    float* ns      = (float*)w;  w += align256((size_t)2 * NN * 4);
    float* nd      = (float*)w;  w += align256((size_t)2 * NN * 4);
    int*   cnt     = (int*)w;    w += align256((size_t)4 * NN * 4);
    int*   csr_off = (int*)w;    w += align256((size_t)(2 * NN + 1) * 4);
    int*   csr_cur = (int*)w;    w += align256((size_t)2 * NN * 4);
    int*   csr_src = (int*)w;    w += align256((size_t)2 * EE * 4);      // 6.4 MB
    int*   btot    = (int*)w;    w += align256((size_t)NB2 * 4);
    int*   bbase   = (int*)w;    w += align256((size_t)NB2 * 4);
    float* pcls    = (float*)w;  w += align256((size_t)NTB * 4);
    float* pdom    = (float*)w;  w += align256((size_t)2 * NTB * 4);
    int*   ctr     = (int*)w;    w += align256((size_t)32 * 4);

    const int TB = 256;
    hipMemsetAsync(cnt, 0, (size_t)4 * NN * 4, stream);
    k_cast_wt<INF><<<(INF * HH + TB - 1) / TB, TB, 0, stream>>>(W0, W0t);
    k_cast_wt<HH><<<(HH * HH + TB - 1) / TB, TB, 0, stream>>>(W1, W1t);
    k_cast_wtail<<<(16 * HH + TB - 1) / TB, TB, 0, stream>>>(Wfc, Wd, Wt1);
    k_cast_wtail2<<<(16 * HH + TB - 1) / TB, TB, 0, stream>>>(Wd, Wt2);

    // batched CSR prep for both graphs
    k_degrees2<<<(2 * EE + TB - 1) / TB, TB, 0, stream>>>(src_s, dst_s, src_t, dst_t, cnt);
    k_scan_blk<<<NB2, TB, 0, stream>>>(cnt, csr_off, btot);
    k_scan_tops<<<1, 512, 0, stream>>>(btot, bbase, csr_off);
    k_scan_fin<<<NB2, TB, 0, stream>>>(csr_off, bbase, csr_cur, cnt, ns, nd, ctr);
    k_fill2<<<(2 * EE + TB - 1) / TB, TB, 0, stream>>>(src_s, dst_s, src_t, dst_t,
                                                       csr_cur, csr_src);

    const int GB = (NN + 127) / 128;   // 391
    for (int g = 0; g < 2; ++g) {
        const float* feats = g ? features_t : features_s;
        const int*   offg  = csr_off + (size_t)g * NN;
        const float* nsg   = ns + (size_t)g * NN;
        const float* ndg   = nd + (size_t)g * NN;

        k_gemm<INF, true><<<GB, TB, 0, stream>>>(feats, W0t, nsg, y2);
        k_spmm3<<<SPMM_BLOCKS, TB, 0, stream>>>(y2, offg, csr_src, ndg, b0, h0,
                                                ctr + g * 16);
        k_gemm<HH, false><<<GB, TB, 0, stream>>>(h0, W1t, nsg, y2);
        k_spmm3<<<SPMM_BLOCKS, TB, 0, stream>>>(y2, offg, csr_src, ndg, b1, h1,
                                                ctr + g * 16 + 8);
        k_tail_mfma<<<NTB, TB, 0, stream>>>(h0, h1, Wt1, Wt2, bfc, bd, labels_s, g,
                                            pcls, pdom);
    }
    k_finalize<<<1, TB, 0, stream>>>(pcls, pdom, out);
}

// Round 7
// 913.506 us; speedup vs baseline: 1.5026x; 1.5026x over previous
//
#include <hip/hip_runtime.h>
#include <cstdint>
#include <cstddef>

#define NN 50000
#define EE 800000
#define INF 512
#define HH  256
#define CC  10
#define NB2 391            // ceil(2*NN/256) scan blocks
#define NTB 782            // ceil(NN/64)  tail blocks
#define SPMM_BLOCKS 1600   // 200 blocks per column group x 8 groups

using bfrag = __attribute__((ext_vector_type(8))) __bf16;
using f32x4 = __attribute__((ext_vector_type(4))) float;

__device__ inline unsigned short f2bf(float x) {
    unsigned u = __builtin_bit_cast(unsigned, x);
    unsigned r = u + 0x7FFFu + ((u >> 16) & 1u);
    return (unsigned short)(r >> 16);
}
__device__ inline float bf2f(unsigned short h) {
    return __builtin_bit_cast(float, (unsigned)h << 16);
}

// ---------------------------------------------------------------- weight casts
template<int K>
__global__ void k_cast_wt(const float* __restrict__ W, ushort* __restrict__ Wt) {
    int idx = blockIdx.x * blockDim.x + threadIdx.x;
    if (idx >= K * HH) return;
    int n = idx / K, k = idx % K;
    Wt[idx] = f2bf(W[(size_t)k * HH + n]);
}

__global__ void k_cast_wtail(const float* __restrict__ Wfc, const float* __restrict__ Wd,
                             ushort* __restrict__ Wt1) {
    int idx = blockIdx.x * blockDim.x + threadIdx.x;
    if (idx >= 16 * HH) return;
    int n = idx >> 8, k = idx & 255;
    float v = 0.f;
    if (n < 10)       v = Wfc[(size_t)k * 10 + n];
    else if (n < 12)  v = Wd[(size_t)(HH + k) * 2 + (n - 10)];
    Wt1[idx] = f2bf(v);
}

__global__ void k_cast_wtail2(const float* __restrict__ Wd, ushort* __restrict__ Wt2) {
    int idx = blockIdx.x * blockDim.x + threadIdx.x;
    if (idx >= 16 * HH) return;
    int n = idx >> 8, k = idx & 255;
    float v = (n < 2) ? Wd[(size_t)k * 2 + n] : 0.f;
    Wt2[idx] = f2bf(v);
}

// ---------------------------------------------------------------- degrees (both graphs)
// cnt layout: [out_s][in_s][out_t][in_t], each NN
__global__ void k_degrees2(const int* __restrict__ src_s, const int* __restrict__ dst_s,
                           const int* __restrict__ src_t, const int* __restrict__ dst_t,
                           int* __restrict__ cnt) {
    int e = blockIdx.x * blockDim.x + threadIdx.x;
    if (e < EE) {
        atomicAdd(&cnt[src_s[e]], 1);
        atomicAdd(&cnt[NN + dst_s[e]], 1);
    } else if (e < 2 * EE) {
        int e2 = e - EE;
        atomicAdd(&cnt[2 * NN + src_t[e2]], 1);
        atomicAdd(&cnt[3 * NN + dst_t[e2]], 1);
    }
}

// ------------------------------------------------- 3-phase scan over in-degrees (2NN)
__global__ void k_scan_blk(const int* __restrict__ cnt, int* __restrict__ off,
                           int* __restrict__ btot) {
    __shared__ int wsum[4];
    int tid = threadIdx.x, lane = tid & 63, wid = tid >> 6;
    int i = blockIdx.x * 256 + tid;
    int v = 0;
    if (i < 2 * NN) v = (i < NN) ? cnt[NN + i] : cnt[2 * NN + i];
    int s = v;
    #pragma unroll
    for (int o = 1; o < 64; o <<= 1) {
        int t = __shfl_up(s, o, 64);
        if (lane >= o) s += t;
    }
    if (lane == 63) wsum[wid] = s;
    __syncthreads();
    if (tid == 0) {
        int a = 0;
        #pragma unroll
        for (int w2 = 0; w2 < 4; ++w2) { int t = wsum[w2]; wsum[w2] = a; a += t; }
        btot[blockIdx.x] = a;
    }
    __syncthreads();
    if (i < 2 * NN) off[i] = wsum[wid] + s - v;
}

__global__ void k_scan_tops(const int* __restrict__ btot, int* __restrict__ bbase,
                            int* __restrict__ off) {
    __shared__ int wsum[8];
    int tid = threadIdx.x, lane = tid & 63, wid = tid >> 6;
    int v = (tid < NB2) ? btot[tid] : 0;
    int s = v;
    #pragma unroll
    for (int o = 1; o < 64; o <<= 1) {
        int t = __shfl_up(s, o, 64);
        if (lane >= o) s += t;
    }
    if (lane == 63) wsum[wid] = s;
    __syncthreads();
    if (tid == 0) {
        int a = 0;
        #pragma unroll
        for (int w2 = 0; w2 < 8; ++w2) { int t = wsum[w2]; wsum[w2] = a; a += t; }
        off[2 * NN] = a;
    }
    __syncthreads();
    if (tid < NB2) bbase[tid] = wsum[wid] + s - v;
}

// fixup + norms (both graphs) + cur copy
__global__ void k_scan_fin(int* __restrict__ off, const int* __restrict__ bbase,
                           int* __restrict__ cur, const int* __restrict__ cnt,
                           float* __restrict__ ns, float* __restrict__ nd) {
    int i = blockIdx.x * blockDim.x + threadIdx.x;
    if (i >= 2 * NN) return;
    int o = off[i] + bbase[i >> 8];
    off[i] = o;
    cur[i] = o;
    int co = (i < NN) ? cnt[i] : cnt[NN + i];          // out-degree
    int ci = (i < NN) ? cnt[NN + i] : cnt[2 * NN + i]; // in-degree
    ns[i] = 1.0f / sqrtf(fmaxf((float)co, 1.0f));
    nd[i] = 1.0f / sqrtf(fmaxf((float)ci, 1.0f));
}

__global__ void k_fill2(const int* __restrict__ src_s, const int* __restrict__ dst_s,
                        const int* __restrict__ src_t, const int* __restrict__ dst_t,
                        int* __restrict__ cur, int* __restrict__ csr_src) {
    int e = blockIdx.x * blockDim.x + threadIdx.x;
    if (e < EE) {
        int p = atomicAdd(&cur[dst_s[e]], 1);
        csr_src[p] = src_s[e];
    } else if (e < 2 * EE) {
        int e2 = e - EE;
        int p = atomicAdd(&cur[NN + dst_t[e2]], 1);
        csr_src[p] = src_t[e2];
    }
}

// ---------------------------------------------------------------- MFMA GEMM
// BM=128, BN=256. y2 output in grouped layout [8][NN][32].
template<int K, bool F32A>
__global__ __launch_bounds__(256, 2) void k_gemm(
        const void* __restrict__ Ap, const ushort* __restrict__ Bt,
        const float* __restrict__ ns, ushort* __restrict__ y2) {
    __shared__ ushort As[128 * 64];
    __shared__ ushort Bs[256 * 64];
    const int m0 = blockIdx.x * 128;
    const int t = threadIdx.x;
    const int wid = t >> 6, lane = t & 63;
    const int wr = (wid & 1) * 64;
    const int wc = (wid >> 1) * 128;
    const int l15 = lane & 15, lg = lane >> 4;

    f32x4 acc[4][8];
    #pragma unroll
    for (int m = 0; m < 4; ++m)
        #pragma unroll
        for (int n = 0; n < 8; ++n)
            acc[m][n] = {0.f, 0.f, 0.f, 0.f};

    const int srow = t >> 3;
    const int schunk = t & 7;

    for (int k0 = 0; k0 < K; k0 += 64) {
        #pragma unroll
        for (int i = 0; i < 4; ++i) {        // A tile 128x64
            int row = srow + i * 32;
            int sw = ((schunk ^ (row & 7)) * 8);
            int m = m0 + row; if (m >= NN) m = NN - 1;
            uint4 va;
            if constexpr (F32A) {
                const float* ap = (const float*)Ap + (size_t)m * K + k0 + schunk * 8;
                float4 f0 = *reinterpret_cast<const float4*>(ap);
                float4 f1 = *reinterpret_cast<const float4*>(ap + 4);
                va.x = (unsigned)f2bf(f0.x) | ((unsigned)f2bf(f0.y) << 16);
                va.y = (unsigned)f2bf(f0.z) | ((unsigned)f2bf(f0.w) << 16);
                va.z = (unsigned)f2bf(f1.x) | ((unsigned)f2bf(f1.y) << 16);
                va.w = (unsigned)f2bf(f1.z) | ((unsigned)f2bf(f1.w) << 16);
            } else {
                va = *reinterpret_cast<const uint4*>((const ushort*)Ap + (size_t)m * K + k0 + schunk * 8);
            }
            *reinterpret_cast<uint4*>(&As[row * 64 + sw]) = va;
        }
        #pragma unroll
        for (int i = 0; i < 8; ++i) {        // B tile 256x64
            int row = srow + i * 32;
            int sw = ((schunk ^ (row & 7)) * 8);
            uint4 vb = *reinterpret_cast<const uint4*>(&Bt[(size_t)row * K + k0 + schunk * 8]);
            *reinterpret_cast<uint4*>(&Bs[row * 64 + sw]) = vb;
        }
        __syncthreads();
        #pragma unroll
        for (int kk = 0; kk < 64; kk += 32) {
            const int kc = kk >> 3;
            bfrag af[4];
            #pragma unroll
            for (int m = 0; m < 4; ++m) {
                int row = wr + m * 16 + l15;
                af[m] = *reinterpret_cast<const bfrag*>(&As[row * 64 + (((lg + kc) ^ (row & 7)) * 8)]);
            }
            #pragma unroll
            for (int n = 0; n < 8; ++n) {
                int row = wc + n * 16 + l15;
                bfrag bg = *reinterpret_cast<const bfrag*>(&Bs[row * 64 + (((lg + kc) ^ (row & 7)) * 8)]);
                #pragma unroll
                for (int m = 0; m < 4; ++m)
                    acc[m][n] = __builtin_amdgcn_mfma_f32_16x16x32_bf16(af[m], bg, acc[m][n], 0, 0, 0);
            }
        }
        __syncthreads();
    }
    #pragma unroll
    for (int m = 0; m < 4; ++m) {
        #pragma unroll
        for (int r = 0; r < 4; ++r) {
            int row = m0 + wr + m * 16 + lg * 4 + r;
            if (row >= NN) continue;
            float nsv = ns[row];
            #pragma unroll
            for (int n = 0; n < 8; ++n) {
                int col = wc + n * 16 + l15;
                int grp = col >> 5, colw = col & 31;
                y2[(size_t)grp * NN * 32 + (size_t)row * 32 + colw] = f2bf(acc[m][n][r] * nsv);
            }
        }
    }
}

// ------------------------------------------------- SpMM: grouped y2, 4-chain MLP
// grp = blockIdx.x & 7 (round-robin block->XCD dispatch): each XCD's blocks gather
// from one contiguous 3.2MB y2 slice -> L2-resident. Wave-independent (no barriers,
// no atomics). Each 4-lane slot owns 4 nodes with interleaved edge chains.
__device__ inline void add8(float* a, uint4 v) {
    a[0] += __builtin_bit_cast(float, v.x << 16);
    a[1] += __builtin_bit_cast(float, v.x & 0xffff0000u);
    a[2] += __builtin_bit_cast(float, v.y << 16);
    a[3] += __builtin_bit_cast(float, v.y & 0xffff0000u);
    a[4] += __builtin_bit_cast(float, v.z << 16);
    a[5] += __builtin_bit_cast(float, v.z & 0xffff0000u);
    a[6] += __builtin_bit_cast(float, v.w << 16);
    a[7] += __builtin_bit_cast(float, v.w & 0xffff0000u);
}

__global__ __launch_bounds__(256) void k_spmm4(
        const ushort* __restrict__ y2, const int* __restrict__ off,
        const int* __restrict__ csr_src, const float* __restrict__ nd_arr,
        const float* __restrict__ bias, ushort* __restrict__ h_out) {
    const int grp = blockIdx.x & 7;
    const int blk = blockIdx.x >> 3;          // 0..199
    const int tid = threadIdx.x;
    const int lane = tid & 63, wid = tid >> 6;
    const int slot = lane >> 2;               // 0..15
    const int sub = lane & 3;                 // 16B sub-chunk of the 32-col slice
    const ushort* ybase = y2 + (size_t)grp * NN * 32 + sub * 8;

    float bia[8];
    #pragma unroll
    for (int j = 0; j < 8; ++j) bia[j] = bias[grp * 32 + sub * 8 + j];

    // wave covers 64 contiguous nodes; grid covers 200*4*64 = 51200 >= NN in one sweep
    const int nb = (blk * 4 + wid) * 64;

    int e[4], e1[4], nidx[4];
    float a[4][8];
    #pragma unroll
    for (int c = 0; c < 4; ++c) {
        nidx[c] = nb + c * 16 + slot;
        bool v = nidx[c] < NN;
        e[c]  = v ? off[nidx[c]] : 0;
        e1[c] = v ? off[nidx[c] + 1] : 0;
        #pragma unroll
        for (int j = 0; j < 8; ++j) a[c][j] = 0.f;
    }

    while ((e[0] < e1[0]) | (e[1] < e1[1]) | (e[2] < e1[2]) | (e[3] < e1[3])) {
        uint4 v0, v1, v2, v3;
        bool d0 = e[0] < e1[0], d1 = e[1] < e1[1], d2 = e[2] < e1[2], d3 = e[3] < e1[3];
        if (d0) { int s = csr_src[e[0]]; v0 = *reinterpret_cast<const uint4*>(&ybase[(size_t)s * 32]); }
        if (d1) { int s = csr_src[e[1]]; v1 = *reinterpret_cast<const uint4*>(&ybase[(size_t)s * 32]); }
        if (d2) { int s = csr_src[e[2]]; v2 = *reinterpret_cast<const uint4*>(&ybase[(size_t)s * 32]); }
        if (d3) { int s = csr_src[e[3]]; v3 = *reinterpret_cast<const uint4*>(&ybase[(size_t)s * 32]); }
        if (d0) { add8(a[0], v0); ++e[0]; }
        if (d1) { add8(a[1], v1); ++e[1]; }
        if (d2) { add8(a[2], v2); ++e[2]; }
        if (d3) { add8(a[3], v3); ++e[3]; }
    }

    #pragma unroll
    for (int c = 0; c < 4; ++c) {
        int n = nidx[c];
        if (n >= NN) continue;
        float nd = nd_arr[n];
        ushort r[8];
        #pragma unroll
        for (int j = 0; j < 8; ++j) r[j] = f2bf(fmaxf(a[c][j] * nd + bia[j], 0.f));
        uint4 pk;
        pk.x = (unsigned)r[0] | ((unsigned)r[1] << 16);
        pk.y = (unsigned)r[2] | ((unsigned)r[3] << 16);
        pk.z = (unsigned)r[4] | ((unsigned)r[5] << 16);
        pk.w = (unsigned)r[6] | ((unsigned)r[7] << 16);
        *reinterpret_cast<uint4*>(&h_out[(size_t)n * 256 + grp * 32 + sub * 8]) = pk;
    }
}

// ------------------------------------------------- MFMA tail: fc + dlog + losses
__global__ __launch_bounds__(256) void k_tail_mfma(
        const ushort* __restrict__ h0, const ushort* __restrict__ h1,
        const ushort* __restrict__ Wt1, const ushort* __restrict__ Wt2,
        const float* __restrict__ bfc, const float* __restrict__ bd,
        const int* __restrict__ labels, int g,
        float* __restrict__ pcls, float* __restrict__ pdom) {
    __shared__ float sT1[4][16][17];
    __shared__ float sT2[4][16][17];
    __shared__ float sc[4], sd[4];
    const int tid = threadIdx.x;
    const int wid = tid >> 6, lane = tid & 63;
    const int l15 = lane & 15, lg = lane >> 4;
    const int base = blockIdx.x * 64 + wid * 16;

    int arow = base + l15; if (arow >= NN) arow = NN - 1;
    const ushort* a1 = h1 + (size_t)arow * 256 + lg * 8;
    const ushort* a0 = h0 + (size_t)arow * 256 + lg * 8;
    const ushort* b1 = Wt1 + (size_t)l15 * 256 + lg * 8;
    const ushort* b2 = Wt2 + (size_t)l15 * 256 + lg * 8;
    f32x4 acc1 = {0.f, 0.f, 0.f, 0.f};
    f32x4 acc2 = {0.f, 0.f, 0.f, 0.f};
    #pragma unroll
    for (int kk = 0; kk < 8; ++kk) {
        bfrag af1 = *reinterpret_cast<const bfrag*>(a1 + kk * 32);
        bfrag bg1 = *reinterpret_cast<const bfrag*>(b1 + kk * 32);
        acc1 = __builtin_amdgcn_mfma_f32_16x16x32_bf16(af1, bg1, acc1, 0, 0, 0);
        bfrag af0 = *reinterpret_cast<const bfrag*>(a0 + kk * 32);
        bfrag bg2 = *reinterpret_cast<const bfrag*>(b2 + kk * 32);
        acc2 = __builtin_amdgcn_mfma_f32_16x16x32_bf16(af0, bg2, acc2, 0, 0, 0);
    }
    #pragma unroll
    for (int j = 0; j < 4; ++j) {
        sT1[wid][lg * 4 + j][l15] = acc1[j];
        sT2[wid][lg * 4 + j][l15] = acc2[j];
    }
    __syncthreads();

    float cls = 0.f, dom = 0.f;
    int n = base + lane;
    if (lane < 16 && n < NN) {
        float lgt[10];
        #pragma unroll
        for (int c = 0; c < 10; ++c) lgt[c] = sT1[wid][lane][c] + bfc[c];
        float dl0 = bd[0] + sT2[wid][lane][0] + sT1[wid][lane][10];
        float dl1 = bd[1] + sT2[wid][lane][1] + sT1[wid][lane][11];
        if (g == 0) {
            float m = lgt[0];
            #pragma unroll
            for (int c = 1; c < 10; ++c) m = fmaxf(m, lgt[c]);
            float s = 0.f;
            #pragma unroll
            for (int c = 0; c < 10; ++c) s += expf(lgt[c] - m);
            int lab = labels[n];
            float tgt = lgt[0];
            #pragma unroll
            for (int c = 1; c < 10; ++c) tgt = (c == lab) ? lgt[c] : tgt;
            cls = -(tgt - (m + logf(s)));
        }
        float m2 = fmaxf(dl0, dl1);
        float lse2 = m2 + logf(expf(dl0 - m2) + expf(dl1 - m2));
        dom = -((g ? dl1 : dl0) - lse2);
    }
    #pragma unroll
    for (int o = 1; o < 16; o <<= 1) {
        cls += __shfl_xor(cls, o, 64);
        dom += __shfl_xor(dom, o, 64);
    }
    if (lane == 0) { sc[wid] = cls; sd[wid] = dom; }
    __syncthreads();
    if (tid == 0) {
        float c = sc[0] + sc[1] + sc[2] + sc[3];
        float d = sd[0] + sd[1] + sd[2] + sd[3];
        if (g == 0) pcls[blockIdx.x] = c;
        pdom[g * NTB + blockIdx.x] = d;
    }
}

__global__ void k_finalize(const float* __restrict__ pcls, const float* __restrict__ pdom,
                           float* __restrict__ out) {
    __shared__ float sc[4], sd[4];
    int tid = threadIdx.x, lane = tid & 63, wid = tid >> 6;
    float c = 0.f, d = 0.f;
    for (int i = tid; i < NTB; i += 256) c += pcls[i];
    for (int i = tid; i < 2 * NTB; i += 256) d += pdom[i];
    #pragma unroll
    for (int o = 32; o; o >>= 1) {
        c += __shfl_xor(c, o, 64);
        d += __shfl_xor(d, o, 64);
    }
    if (lane == 0) { sc[wid] = c; sd[wid] = d; }
    __syncthreads();
    if (tid == 0) {
        float ct = sc[0] + sc[1] + sc[2] + sc[3];
        float dt = sd[0] + sd[1] + sd[2] + sd[3];
        out[0] = ct / (float)NN + 0.01f * (dt / (float)(2 * NN));
    }
}

// ---------------------------------------------------------------- launch
extern "C" void kernel_launch(void* const* d_in, const int* in_sizes, int n_in,
                              void* d_out, int out_size, void* d_ws, size_t ws_size,
                              hipStream_t stream) {
    const float* features_s = (const float*)d_in[0];
    const int*   labels_s   = (const int*)d_in[1];
    const float* features_t = (const float*)d_in[2];
    const int*   src_s      = (const int*)d_in[3];
    const int*   dst_s      = (const int*)d_in[4];
    const int*   src_t      = (const int*)d_in[5];
    const int*   dst_t      = (const int*)d_in[6];
    const float* W0         = (const float*)d_in[7];
    const float* b0         = (const float*)d_in[8];
    const float* W1         = (const float*)d_in[9];
    const float* b1         = (const float*)d_in[10];
    const float* Wfc        = (const float*)d_in[11];
    const float* bfc        = (const float*)d_in[12];
    const float* Wd         = (const float*)d_in[13];
    const float* bd         = (const float*)d_in[14];
    float* out = (float*)d_out;

    auto align256 = [](size_t x) { return (x + 255) & ~(size_t)255; };
    char* w = (char*)d_ws;
    ushort* h0     = (ushort*)w; w += align256((size_t)NN * HH * 2);     // 25.6 MB
    ushort* h1     = (ushort*)w; w += align256((size_t)NN * HH * 2);     // 25.6 MB
    ushort* y2     = (ushort*)w; w += align256((size_t)NN * HH * 2);     // 25.6 MB grouped
    ushort* W0t    = (ushort*)w; w += align256((size_t)INF * HH * 2);
    ushort* W1t    = (ushort*)w; w += align256((size_t)HH * HH * 2);
    ushort* Wt1    = (ushort*)w; w += align256((size_t)16 * HH * 2);
    ushort* Wt2    = (ushort*)w; w += align256((size_t)16 * HH * 2);
    float* ns      = (float*)w;  w += align256((size_t)2 * NN * 4);
    float* nd      = (float*)w;  w += align256((size_t)2 * NN * 4);
    int*   cnt     = (int*)w;    w += align256((size_t)4 * NN * 4);
    int*   csr_off = (int*)w;    w += align256((size_t)(2 * NN + 1) * 4);
    int*   csr_cur = (int*)w;    w += align256((size_t)2 * NN * 4);
    int*   csr_src = (int*)w;    w += align256((size_t)2 * EE * 4);      // 6.4 MB
    int*   btot    = (int*)w;    w += align256((size_t)NB2 * 4);
    int*   bbase   = (int*)w;    w += align256((size_t)NB2 * 4);
    float* pcls    = (float*)w;  w += align256((size_t)NTB * 4);
    float* pdom    = (float*)w;  w += align256((size_t)2 * NTB * 4);

    const int TB = 256;
    hipMemsetAsync(cnt, 0, (size_t)4 * NN * 4, stream);
    k_cast_wt<INF><<<(INF * HH + TB - 1) / TB, TB, 0, stream>>>(W0, W0t);
    k_cast_wt<HH><<<(HH * HH + TB - 1) / TB, TB, 0, stream>>>(W1, W1t);
    k_cast_wtail<<<(16 * HH + TB - 1) / TB, TB, 0, stream>>>(Wfc, Wd, Wt1);
    k_cast_wtail2<<<(16 * HH + TB - 1) / TB, TB, 0, stream>>>(Wd, Wt2);

    // batched CSR prep for both graphs
    k_degrees2<<<(2 * EE + TB - 1) / TB, TB, 0, stream>>>(src_s, dst_s, src_t, dst_t, cnt);
    k_scan_blk<<<NB2, TB, 0, stream>>>(cnt, csr_off, btot);
    k_scan_tops<<<1, 512, 0, stream>>>(btot, bbase, csr_off);
    k_scan_fin<<<NB2, TB, 0, stream>>>(csr_off, bbase, csr_cur, cnt, ns, nd);
    k_fill2<<<(2 * EE + TB - 1) / TB, TB, 0, stream>>>(src_s, dst_s, src_t, dst_t,
                                                       csr_cur, csr_src);

    const int GB = (NN + 127) / 128;   // 391
    for (int g = 0; g < 2; ++g) {
        const float* feats = g ? features_t : features_s;
        const int*   offg  = csr_off + (size_t)g * NN;
        const float* nsg   = ns + (size_t)g * NN;
        const float* ndg   = nd + (size_t)g * NN;

        k_gemm<INF, true><<<GB, TB, 0, stream>>>(feats, W0t, nsg, y2);
        k_spmm4<<<SPMM_BLOCKS, TB, 0, stream>>>(y2, offg, csr_src, ndg, b0, h0);
        k_gemm<HH, false><<<GB, TB, 0, stream>>>(h0, W1t, nsg, y2);
        k_spmm4<<<SPMM_BLOCKS, TB, 0, stream>>>(y2, offg, csr_src, ndg, b1, h1);
        k_tail_mfma<<<NTB, TB, 0, stream>>>(h0, h1, Wt1, Wt2, bfc, bd, labels_s, g,
                                            pcls, pdom);
    }
    k_finalize<<<1, TB, 0, stream>>>(pcls, pdom, out);
}

// Round 8
// 678.117 us; speedup vs baseline: 2.0242x; 1.3471x over previous
//
#include <hip/hip_runtime.h>
#include <cstdint>
#include <cstddef>

#define NN 50000
#define EE 800000
#define INF 512
#define HH  256
#define CC  10
#define NB2 391            // ceil(2*NN/256) scan blocks
#define NTB 782            // ceil(NN/64)  tail blocks
#define SPMM_BLOCKS 1600   // 200 blocks per column group x 8 groups
#define NFB 104            // fill blocks per partition
#define PSZ 12500          // nodes per fill partition (2*NN/8)

using bfrag = __attribute__((ext_vector_type(8))) __bf16;
using f32x4 = __attribute__((ext_vector_type(4))) float;

__device__ inline unsigned short f2bf(float x) {
    unsigned u = __builtin_bit_cast(unsigned, x);
    unsigned r = u + 0x7FFFu + ((u >> 16) & 1u);
    return (unsigned short)(r >> 16);
}
__device__ inline float bf2f(unsigned short h) {
    return __builtin_bit_cast(float, (unsigned)h << 16);
}

// ---------------------------------------------------------------- weight casts
template<int K>
__global__ void k_cast_wt(const float* __restrict__ W, ushort* __restrict__ Wt) {
    int idx = blockIdx.x * blockDim.x + threadIdx.x;
    if (idx >= K * HH) return;
    int n = idx / K, k = idx % K;
    Wt[idx] = f2bf(W[(size_t)k * HH + n]);
}

__global__ void k_cast_wtail(const float* __restrict__ Wfc, const float* __restrict__ Wd,
                             ushort* __restrict__ Wt1) {
    int idx = blockIdx.x * blockDim.x + threadIdx.x;
    if (idx >= 16 * HH) return;
    int n = idx >> 8, k = idx & 255;
    float v = 0.f;
    if (n < 10)       v = Wfc[(size_t)k * 10 + n];
    else if (n < 12)  v = Wd[(size_t)(HH + k) * 2 + (n - 10)];
    Wt1[idx] = f2bf(v);
}

__global__ void k_cast_wtail2(const float* __restrict__ Wd, ushort* __restrict__ Wt2) {
    int idx = blockIdx.x * blockDim.x + threadIdx.x;
    if (idx >= 16 * HH) return;
    int n = idx >> 8, k = idx & 255;
    float v = (n < 2) ? Wd[(size_t)k * 2 + n] : 0.f;
    Wt2[idx] = f2bf(v);
}

// ---------------------------------------------------------------- degrees (both graphs)
// cnt layout: [out_s][in_s][out_t][in_t], each NN
__global__ void k_degrees2(const int* __restrict__ src_s, const int* __restrict__ dst_s,
                           const int* __restrict__ src_t, const int* __restrict__ dst_t,
                           int* __restrict__ cnt) {
    int e = blockIdx.x * blockDim.x + threadIdx.x;
    if (e < EE) {
        atomicAdd(&cnt[src_s[e]], 1);
        atomicAdd(&cnt[NN + dst_s[e]], 1);
    } else if (e < 2 * EE) {
        int e2 = e - EE;
        atomicAdd(&cnt[2 * NN + src_t[e2]], 1);
        atomicAdd(&cnt[3 * NN + dst_t[e2]], 1);
    }
}

// ------------------------------------------------- 3-phase scan over in-degrees (2NN)
__global__ void k_scan_blk(const int* __restrict__ cnt, int* __restrict__ off,
                           int* __restrict__ btot) {
    __shared__ int wsum[4];
    int tid = threadIdx.x, lane = tid & 63, wid = tid >> 6;
    int i = blockIdx.x * 256 + tid;
    int v = 0;
    if (i < 2 * NN) v = (i < NN) ? cnt[NN + i] : cnt[2 * NN + i];
    int s = v;
    #pragma unroll
    for (int o = 1; o < 64; o <<= 1) {
        int t = __shfl_up(s, o, 64);
        if (lane >= o) s += t;
    }
    if (lane == 63) wsum[wid] = s;
    __syncthreads();
    if (tid == 0) {
        int a = 0;
        #pragma unroll
        for (int w2 = 0; w2 < 4; ++w2) { int t = wsum[w2]; wsum[w2] = a; a += t; }
        btot[blockIdx.x] = a;
    }
    __syncthreads();
    if (i < 2 * NN) off[i] = wsum[wid] + s - v;
}

__global__ void k_scan_tops(const int* __restrict__ btot, int* __restrict__ bbase,
                            int* __restrict__ off) {
    __shared__ int wsum[8];
    int tid = threadIdx.x, lane = tid & 63, wid = tid >> 6;
    int v = (tid < NB2) ? btot[tid] : 0;
    int s = v;
    #pragma unroll
    for (int o = 1; o < 64; o <<= 1) {
        int t = __shfl_up(s, o, 64);
        if (lane >= o) s += t;
    }
    if (lane == 63) wsum[wid] = s;
    __syncthreads();
    if (tid == 0) {
        int a = 0;
        #pragma unroll
        for (int w2 = 0; w2 < 8; ++w2) { int t = wsum[w2]; wsum[w2] = a; a += t; }
        off[2 * NN] = a;
    }
    __syncthreads();
    if (tid < NB2) bbase[tid] = wsum[wid] + s - v;
}

// fixup + norms (both graphs) + cur copy
__global__ void k_scan_fin(int* __restrict__ off, const int* __restrict__ bbase,
                           int* __restrict__ cur, const int* __restrict__ cnt,
                           float* __restrict__ ns, float* __restrict__ nd) {
    int i = blockIdx.x * blockDim.x + threadIdx.x;
    if (i >= 2 * NN) return;
    int o = off[i] + bbase[i >> 8];
    off[i] = o;
    cur[i] = o;
    int co = (i < NN) ? cnt[i] : cnt[NN + i];          // out-degree
    int ci = (i < NN) ? cnt[NN + i] : cnt[2 * NN + i]; // in-degree
    ns[i] = 1.0f / sqrtf(fmaxf((float)co, 1.0f));
    nd[i] = 1.0f / sqrtf(fmaxf((float)ci, 1.0f));
}

// ------------------------------------------------- partitioned CSR fill
// partition p = blockIdx&7 (XCD-pinned) owns nodes [p*PSZ, (p+1)*PSZ).
// Each partition scans all 2E edges (coalesced) and writes only its own
// contiguous ~800KB csr region -> lines fill completely inside one L2.
__global__ __launch_bounds__(256) void k_fill_part(
        const int* __restrict__ src_s, const int* __restrict__ dst_s,
        const int* __restrict__ src_t, const int* __restrict__ dst_t,
        int* __restrict__ cur, int* __restrict__ csr_src) {
    const int p = blockIdx.x & 7;
    const int blk = blockIdx.x >> 3;      // 0..NFB-1
    const unsigned lo = p * PSZ;
    for (int e = blk * 256 + (int)threadIdx.x; e < 2 * EE; e += NFB * 256) {
        int node, sv;
        if (e < EE) {
            node = dst_s[e];
            sv = src_s[e];
        } else {
            node = NN + dst_t[e - EE];
            sv = src_t[e - EE];
        }
        if ((unsigned)(node - lo) < (unsigned)PSZ) {
            int pos = atomicAdd(&cur[node], 1);
            csr_src[pos] = sv;
        }
    }
}

// ---------------------------------------------------------------- MFMA GEMM
// BM=128, BN=256. y2 output in grouped layout [8][NN][32].
template<int K, bool F32A>
__global__ __launch_bounds__(256, 2) void k_gemm(
        const void* __restrict__ Ap, const ushort* __restrict__ Bt,
        const float* __restrict__ ns, ushort* __restrict__ y2) {
    __shared__ ushort As[128 * 64];
    __shared__ ushort Bs[256 * 64];
    const int m0 = blockIdx.x * 128;
    const int t = threadIdx.x;
    const int wid = t >> 6, lane = t & 63;
    const int wr = (wid & 1) * 64;
    const int wc = (wid >> 1) * 128;
    const int l15 = lane & 15, lg = lane >> 4;

    f32x4 acc[4][8];
    #pragma unroll
    for (int m = 0; m < 4; ++m)
        #pragma unroll
        for (int n = 0; n < 8; ++n)
            acc[m][n] = {0.f, 0.f, 0.f, 0.f};

    const int srow = t >> 3;
    const int schunk = t & 7;

    for (int k0 = 0; k0 < K; k0 += 64) {
        #pragma unroll
        for (int i = 0; i < 4; ++i) {        // A tile 128x64
            int row = srow + i * 32;
            int sw = ((schunk ^ (row & 7)) * 8);
            int m = m0 + row; if (m >= NN) m = NN - 1;
            uint4 va;
            if constexpr (F32A) {
                const float* ap = (const float*)Ap + (size_t)m * K + k0 + schunk * 8;
                float4 f0 = *reinterpret_cast<const float4*>(ap);
                float4 f1 = *reinterpret_cast<const float4*>(ap + 4);
                va.x = (unsigned)f2bf(f0.x) | ((unsigned)f2bf(f0.y) << 16);
                va.y = (unsigned)f2bf(f0.z) | ((unsigned)f2bf(f0.w) << 16);
                va.z = (unsigned)f2bf(f1.x) | ((unsigned)f2bf(f1.y) << 16);
                va.w = (unsigned)f2bf(f1.z) | ((unsigned)f2bf(f1.w) << 16);
            } else {
                va = *reinterpret_cast<const uint4*>((const ushort*)Ap + (size_t)m * K + k0 + schunk * 8);
            }
            *reinterpret_cast<uint4*>(&As[row * 64 + sw]) = va;
        }
        #pragma unroll
        for (int i = 0; i < 8; ++i) {        // B tile 256x64
            int row = srow + i * 32;
            int sw = ((schunk ^ (row & 7)) * 8);
            uint4 vb = *reinterpret_cast<const uint4*>(&Bt[(size_t)row * K + k0 + schunk * 8]);
            *reinterpret_cast<uint4*>(&Bs[row * 64 + sw]) = vb;
        }
        __syncthreads();
        #pragma unroll
        for (int kk = 0; kk < 64; kk += 32) {
            const int kc = kk >> 3;
            bfrag af[4];
            #pragma unroll
            for (int m = 0; m < 4; ++m) {
                int row = wr + m * 16 + l15;
                af[m] = *reinterpret_cast<const bfrag*>(&As[row * 64 + (((lg + kc) ^ (row & 7)) * 8)]);
            }
            #pragma unroll
            for (int n = 0; n < 8; ++n) {
                int row = wc + n * 16 + l15;
                bfrag bg = *reinterpret_cast<const bfrag*>(&Bs[row * 64 + (((lg + kc) ^ (row & 7)) * 8)]);
                #pragma unroll
                for (int m = 0; m < 4; ++m)
                    acc[m][n] = __builtin_amdgcn_mfma_f32_16x16x32_bf16(af[m], bg, acc[m][n], 0, 0, 0);
            }
        }
        __syncthreads();
    }
    #pragma unroll
    for (int m = 0; m < 4; ++m) {
        #pragma unroll
        for (int r = 0; r < 4; ++r) {
            int row = m0 + wr + m * 16 + lg * 4 + r;
            if (row >= NN) continue;
            float nsv = ns[row];
            #pragma unroll
            for (int n = 0; n < 8; ++n) {
                int col = wc + n * 16 + l15;
                int grp = col >> 5, colw = col & 31;
                y2[(size_t)grp * NN * 32 + (size_t)row * 32 + colw] = f2bf(acc[m][n][r] * nsv);
            }
        }
    }
}

// ------------------------------------------------- SpMM: LDS-staged indices
// grp = blockIdx&7 -> contiguous 3.2MB y2 slice L2-resident per XCD.
// Wave stages its 64 contiguous nodes' csr segment into LDS (coalesced),
// then gathers with 4 pipelined chains per lane reading indices from LDS.
__device__ inline void add8(float* a, uint4 v) {
    a[0] += __builtin_bit_cast(float, v.x << 16);
    a[1] += __builtin_bit_cast(float, v.x & 0xffff0000u);
    a[2] += __builtin_bit_cast(float, v.y << 16);
    a[3] += __builtin_bit_cast(float, v.y & 0xffff0000u);
    a[4] += __builtin_bit_cast(float, v.z << 16);
    a[5] += __builtin_bit_cast(float, v.z & 0xffff0000u);
    a[6] += __builtin_bit_cast(float, v.w << 16);
    a[7] += __builtin_bit_cast(float, v.w & 0xffff0000u);
}

#define SCAP 1536

__global__ __launch_bounds__(256) void k_spmm5(
        const ushort* __restrict__ y2, const int* __restrict__ off,
        const int* __restrict__ csr_src, const float* __restrict__ nd_arr,
        const float* __restrict__ bias, ushort* __restrict__ h_out) {
    __shared__ int sidx[4][SCAP];
    const int grp = blockIdx.x & 7;
    const int blk = blockIdx.x >> 3;          // 0..199
    const int tid = threadIdx.x;
    const int lane = tid & 63, wid = tid >> 6;
    const int slot = lane >> 2;               // 0..15
    const int sub = lane & 3;                 // 16B sub-chunk of the 32-col slice
    const ushort* ybase = y2 + (size_t)grp * NN * 32 + sub * 8;

    const int nb = (blk * 4 + wid) * 64;
    int s_wave0 = 0, cnt = 0;
    if (nb < NN) {
        int nend = nb + 64 < NN ? nb + 64 : NN;
        s_wave0 = off[nb];
        cnt = off[nend] - s_wave0;
    }
    int stage = cnt < SCAP ? cnt : SCAP;
    for (int j = lane; j < stage; j += 64)
        sidx[wid][j] = csr_src[s_wave0 + j];
    __syncthreads();

    float bia[8];
    #pragma unroll
    for (int j = 0; j < 8; ++j) bia[j] = bias[grp * 32 + sub * 8 + j];

    int e[4], e1[4], nidx[4], idx[4];
    bool act[4];
    float a[4][8];
    #pragma unroll
    for (int c = 0; c < 4; ++c) {
        nidx[c] = nb + c * 16 + slot;
        bool v = nidx[c] < NN;
        e[c]  = v ? off[nidx[c]] - s_wave0 : 0;
        e1[c] = v ? off[nidx[c] + 1] - s_wave0 : 0;
        #pragma unroll
        for (int j = 0; j < 8; ++j) a[c][j] = 0.f;
        act[c] = e[c] < e1[c];
        if (act[c]) idx[c] = (e[c] < SCAP) ? sidx[wid][e[c]] : csr_src[s_wave0 + e[c]];
    }

    while (act[0] | act[1] | act[2] | act[3]) {
        uint4 v[4];
        bool ca[4];
        #pragma unroll
        for (int c = 0; c < 4; ++c) {
            ca[c] = act[c];
            if (ca[c]) v[c] = *reinterpret_cast<const uint4*>(&ybase[(size_t)idx[c] * 32]);
        }
        // advance + prefetch next indices (overlaps with adds)
        #pragma unroll
        for (int c = 0; c < 4; ++c) {
            if (ca[c]) ++e[c];
            act[c] = e[c] < e1[c];
            if (act[c]) idx[c] = (e[c] < SCAP) ? sidx[wid][e[c]] : csr_src[s_wave0 + e[c]];
        }
        #pragma unroll
        for (int c = 0; c < 4; ++c)
            if (ca[c]) add8(a[c], v[c]);
    }

    #pragma unroll
    for (int c = 0; c < 4; ++c) {
        int n = nidx[c];
        if (n >= NN) continue;
        float nd = nd_arr[n];
        ushort r[8];
        #pragma unroll
        for (int j = 0; j < 8; ++j) r[j] = f2bf(fmaxf(a[c][j] * nd + bia[j], 0.f));
        uint4 pk;
        pk.x = (unsigned)r[0] | ((unsigned)r[1] << 16);
        pk.y = (unsigned)r[2] | ((unsigned)r[3] << 16);
        pk.z = (unsigned)r[4] | ((unsigned)r[5] << 16);
        pk.w = (unsigned)r[6] | ((unsigned)r[7] << 16);
        *reinterpret_cast<uint4*>(&h_out[(size_t)n * 256 + grp * 32 + sub * 8]) = pk;
    }
}

// ------------------------------------------------- MFMA tail: fc + dlog + losses
__global__ __launch_bounds__(256) void k_tail_mfma(
        const ushort* __restrict__ h0, const ushort* __restrict__ h1,
        const ushort* __restrict__ Wt1, const ushort* __restrict__ Wt2,
        const float* __restrict__ bfc, const float* __restrict__ bd,
        const int* __restrict__ labels, int g,
        float* __restrict__ pcls, float* __restrict__ pdom) {
    __shared__ float sT1[4][16][17];
    __shared__ float sT2[4][16][17];
    __shared__ float sc[4], sd[4];
    const int tid = threadIdx.x;
    const int wid = tid >> 6, lane = tid & 63;
    const int l15 = lane & 15, lg = lane >> 4;
    const int base = blockIdx.x * 64 + wid * 16;

    int arow = base + l15; if (arow >= NN) arow = NN - 1;
    const ushort* a1 = h1 + (size_t)arow * 256 + lg * 8;
    const ushort* a0 = h0 + (size_t)arow * 256 + lg * 8;
    const ushort* b1 = Wt1 + (size_t)l15 * 256 + lg * 8;
    const ushort* b2 = Wt2 + (size_t)l15 * 256 + lg * 8;
    f32x4 acc1 = {0.f, 0.f, 0.f, 0.f};
    f32x4 acc2 = {0.f, 0.f, 0.f, 0.f};
    #pragma unroll
    for (int kk = 0; kk < 8; ++kk) {
        bfrag af1 = *reinterpret_cast<const bfrag*>(a1 + kk * 32);
        bfrag bg1 = *reinterpret_cast<const bfrag*>(b1 + kk * 32);
        acc1 = __builtin_amdgcn_mfma_f32_16x16x32_bf16(af1, bg1, acc1, 0, 0, 0);
        bfrag af0 = *reinterpret_cast<const bfrag*>(a0 + kk * 32);
        bfrag bg2 = *reinterpret_cast<const bfrag*>(b2 + kk * 32);
        acc2 = __builtin_amdgcn_mfma_f32_16x16x32_bf16(af0, bg2, acc2, 0, 0, 0);
    }
    #pragma unroll
    for (int j = 0; j < 4; ++j) {
        sT1[wid][lg * 4 + j][l15] = acc1[j];
        sT2[wid][lg * 4 + j][l15] = acc2[j];
    }
    __syncthreads();

    float cls = 0.f, dom = 0.f;
    int n = base + lane;
    if (lane < 16 && n < NN) {
        float lgt[10];
        #pragma unroll
        for (int c = 0; c < 10; ++c) lgt[c] = sT1[wid][lane][c] + bfc[c];
        float dl0 = bd[0] + sT2[wid][lane][0] + sT1[wid][lane][10];
        float dl1 = bd[1] + sT2[wid][lane][1] + sT1[wid][lane][11];
        if (g == 0) {
            float m = lgt[0];
            #pragma unroll
            for (int c = 1; c < 10; ++c) m = fmaxf(m, lgt[c]);
            float s = 0.f;
            #pragma unroll
            for (int c = 0; c < 10; ++c) s += expf(lgt[c] - m);
            int lab = labels[n];
            float tgt = lgt[0];
            #pragma unroll
            for (int c = 1; c < 10; ++c) tgt = (c == lab) ? lgt[c] : tgt;
            cls = -(tgt - (m + logf(s)));
        }
        float m2 = fmaxf(dl0, dl1);
        float lse2 = m2 + logf(expf(dl0 - m2) + expf(dl1 - m2));
        dom = -((g ? dl1 : dl0) - lse2);
    }
    #pragma unroll
    for (int o = 1; o < 16; o <<= 1) {
        cls += __shfl_xor(cls, o, 64);
        dom += __shfl_xor(dom, o, 64);
    }
    if (lane == 0) { sc[wid] = cls; sd[wid] = dom; }
    __syncthreads();
    if (tid == 0) {
        float c = sc[0] + sc[1] + sc[2] + sc[3];
        float d = sd[0] + sd[1] + sd[2] + sd[3];
        if (g == 0) pcls[blockIdx.x] = c;
        pdom[g * NTB + blockIdx.x] = d;
    }
}

__global__ void k_finalize(const float* __restrict__ pcls, const float* __restrict__ pdom,
                           float* __restrict__ out) {
    __shared__ float sc[4], sd[4];
    int tid = threadIdx.x, lane = tid & 63, wid = tid >> 6;
    float c = 0.f, d = 0.f;
    for (int i = tid; i < NTB; i += 256) c += pcls[i];
    for (int i = tid; i < 2 * NTB; i += 256) d += pdom[i];
    #pragma unroll
    for (int o = 32; o; o >>= 1) {
        c += __shfl_xor(c, o, 64);
        d += __shfl_xor(d, o, 64);
    }
    if (lane == 0) { sc[wid] = c; sd[wid] = d; }
    __syncthreads();
    if (tid == 0) {
        float ct = sc[0] + sc[1] + sc[2] + sc[3];
        float dt = sd[0] + sd[1] + sd[2] + sd[3];
        out[0] = ct / (float)NN + 0.01f * (dt / (float)(2 * NN));
    }
}

// ---------------------------------------------------------------- launch
extern "C" void kernel_launch(void* const* d_in, const int* in_sizes, int n_in,
                              void* d_out, int out_size, void* d_ws, size_t ws_size,
                              hipStream_t stream) {
    const float* features_s = (const float*)d_in[0];
    const int*   labels_s   = (const int*)d_in[1];
    const float* features_t = (const float*)d_in[2];
    const int*   src_s      = (const int*)d_in[3];
    const int*   dst_s      = (const int*)d_in[4];
    const int*   src_t      = (const int*)d_in[5];
    const int*   dst_t      = (const int*)d_in[6];
    const float* W0         = (const float*)d_in[7];
    const float* b0         = (const float*)d_in[8];
    const float* W1         = (const float*)d_in[9];
    const float* b1         = (const float*)d_in[10];
    const float* Wfc        = (const float*)d_in[11];
    const float* bfc        = (const float*)d_in[12];
    const float* Wd         = (const float*)d_in[13];
    const float* bd         = (const float*)d_in[14];
    float* out = (float*)d_out;

    auto align256 = [](size_t x) { return (x + 255) & ~(size_t)255; };
    char* w = (char*)d_ws;
    ushort* h0     = (ushort*)w; w += align256((size_t)NN * HH * 2);     // 25.6 MB
    ushort* h1     = (ushort*)w; w += align256((size_t)NN * HH * 2);     // 25.6 MB
    ushort* y2     = (ushort*)w; w += align256((size_t)NN * HH * 2);     // 25.6 MB grouped
    ushort* W0t    = (ushort*)w; w += align256((size_t)INF * HH * 2);
    ushort* W1t    = (ushort*)w; w += align256((size_t)HH * HH * 2);
    ushort* Wt1    = (ushort*)w; w += align256((size_t)16 * HH * 2);
    ushort* Wt2    = (ushort*)w; w += align256((size_t)16 * HH * 2);
    float* ns      = (float*)w;  w += align256((size_t)2 * NN * 4);
    float* nd      = (float*)w;  w += align256((size_t)2 * NN * 4);
    int*   cnt     = (int*)w;    w += align256((size_t)4 * NN * 4);
    int*   csr_off = (int*)w;    w += align256((size_t)(2 * NN + 1) * 4);
    int*   csr_cur = (int*)w;    w += align256((size_t)2 * NN * 4);
    int*   csr_src = (int*)w;    w += align256((size_t)2 * EE * 4);      // 6.4 MB
    int*   btot    = (int*)w;    w += align256((size_t)NB2 * 4);
    int*   bbase   = (int*)w;    w += align256((size_t)NB2 * 4);
    float* pcls    = (float*)w;  w += align256((size_t)NTB * 4);
    float* pdom    = (float*)w;  w += align256((size_t)2 * NTB * 4);

    const int TB = 256;
    hipMemsetAsync(cnt, 0, (size_t)4 * NN * 4, stream);
    k_cast_wt<INF><<<(INF * HH + TB - 1) / TB, TB, 0, stream>>>(W0, W0t);
    k_cast_wt<HH><<<(HH * HH + TB - 1) / TB, TB, 0, stream>>>(W1, W1t);
    k_cast_wtail<<<(16 * HH + TB - 1) / TB, TB, 0, stream>>>(Wfc, Wd, Wt1);
    k_cast_wtail2<<<(16 * HH + TB - 1) / TB, TB, 0, stream>>>(Wd, Wt2);

    // batched CSR prep for both graphs
    k_degrees2<<<(2 * EE + TB - 1) / TB, TB, 0, stream>>>(src_s, dst_s, src_t, dst_t, cnt);
    k_scan_blk<<<NB2, TB, 0, stream>>>(cnt, csr_off, btot);
    k_scan_tops<<<1, 512, 0, stream>>>(btot, bbase, csr_off);
    k_scan_fin<<<NB2, TB, 0, stream>>>(csr_off, bbase, csr_cur, cnt, ns, nd);
    k_fill_part<<<NFB * 8, TB, 0, stream>>>(src_s, dst_s, src_t, dst_t,
                                            csr_cur, csr_src);

    const int GB = (NN + 127) / 128;   // 391
    for (int g = 0; g < 2; ++g) {
        const float* feats = g ? features_t : features_s;
        const int*   offg  = csr_off + (size_t)g * NN;
        const float* nsg   = ns + (size_t)g * NN;
        const float* ndg   = nd + (size_t)g * NN;

        k_gemm<INF, true><<<GB, TB, 0, stream>>>(feats, W0t, nsg, y2);
        k_spmm5<<<SPMM_BLOCKS, TB, 0, stream>>>(y2, offg, csr_src, ndg, b0, h0);
        k_gemm<HH, false><<<GB, TB, 0, stream>>>(h0, W1t, nsg, y2);
        k_spmm5<<<SPMM_BLOCKS, TB, 0, stream>>>(y2, offg, csr_src, ndg, b1, h1);
        k_tail_mfma<<<NTB, TB, 0, stream>>>(h0, h1, Wt1, Wt2, bfc, bd, labels_s, g,
                                            pcls, pdom);
    }
    k_finalize<<<1, TB, 0, stream>>>(pcls, pdom, out);
}

// Round 9
// 616.302 us; speedup vs baseline: 2.2272x; 1.1003x over previous
//
#include <hip/hip_runtime.h>
#include <cstdint>
#include <cstddef>

#define NN 50000
#define EE 800000
#define INF 512
#define HH  256
#define CC  10
#define NB2 391            // ceil(2*NN/256) scan blocks
#define NTB 782            // ceil(NN/64)  tail blocks
#define SPMM_BLOCKS 1600   // 200 blocks per column group x 8 groups
#define NFB 104            // fill blocks per partition
#define PSZ 12500          // nodes per fill partition (2*NN/8)
#define HBIN 12500         // histogram bins per range task
#define HSUB 16            // blocks per histogram task

using bfrag = __attribute__((ext_vector_type(8))) __bf16;
using f32x4 = __attribute__((ext_vector_type(4))) float;

__device__ inline unsigned short f2bf(float x) {
    unsigned u = __builtin_bit_cast(unsigned, x);
    unsigned r = u + 0x7FFFu + ((u >> 16) & 1u);
    return (unsigned short)(r >> 16);
}
__device__ inline float bf2f(unsigned short h) {
    return __builtin_bit_cast(float, (unsigned)h << 16);
}

// ---------------------------------------------------------------- weight casts
template<int K>
__global__ void k_cast_wt(const float* __restrict__ W, ushort* __restrict__ Wt) {
    int idx = blockIdx.x * blockDim.x + threadIdx.x;
    if (idx >= K * HH) return;
    int n = idx / K, k = idx % K;
    Wt[idx] = f2bf(W[(size_t)k * HH + n]);
}

__global__ void k_cast_wtail(const float* __restrict__ Wfc, const float* __restrict__ Wd,
                             ushort* __restrict__ Wt1) {
    int idx = blockIdx.x * blockDim.x + threadIdx.x;
    if (idx >= 16 * HH) return;
    int n = idx >> 8, k = idx & 255;
    float v = 0.f;
    if (n < 10)       v = Wfc[(size_t)k * 10 + n];
    else if (n < 12)  v = Wd[(size_t)(HH + k) * 2 + (n - 10)];
    Wt1[idx] = f2bf(v);
}

__global__ void k_cast_wtail2(const float* __restrict__ Wd, ushort* __restrict__ Wt2) {
    int idx = blockIdx.x * blockDim.x + threadIdx.x;
    if (idx >= 16 * HH) return;
    int n = idx >> 8, k = idx & 255;
    float v = (n < 2) ? Wd[(size_t)k * 2 + n] : 0.f;
    Wt2[idx] = f2bf(v);
}

// ---------------------------------------------------------------- LDS histogram degrees
// task = arr(4) x range(4); HSUB blocks per task. No global atomics: each block
// counts its edge slice for one 12500-node range in LDS, writes partial coalesced.
__global__ __launch_bounds__(256) void k_deghist(
        const int* __restrict__ src_s, const int* __restrict__ dst_s,
        const int* __restrict__ src_t, const int* __restrict__ dst_t,
        int* __restrict__ pcnt) {
    __shared__ int hist[HBIN];
    const int task = blockIdx.x >> 4;    // 0..15
    const int sub  = blockIdx.x & 15;    // 0..15
    const int arr = task >> 2, range = task & 3;
    const int* p = (arr == 0) ? src_s : (arr == 1) ? dst_s : (arr == 2) ? src_t : dst_t;
    const int lo = range * HBIN;
    for (int j = threadIdx.x; j < HBIN; j += 256) hist[j] = 0;
    __syncthreads();
    for (int e = sub * 256 + (int)threadIdx.x; e < EE; e += HSUB * 256) {
        int v = p[e] - lo;
        if ((unsigned)v < (unsigned)HBIN) atomicAdd(&hist[v], 1);
    }
    __syncthreads();
    int* out = pcnt + ((size_t)task * HSUB + sub) * HBIN;
    for (int j = threadIdx.x; j < HBIN; j += 256) out[j] = hist[j];
}

// sum the HSUB partials -> cnt [out_s][in_s][out_t][in_t]
__global__ void k_degsum(const int* __restrict__ pcnt, int* __restrict__ cnt) {
    int g = blockIdx.x * blockDim.x + threadIdx.x;
    if (g >= 4 * NN) return;
    int arr = g / NN;
    int node = g - arr * NN;
    int range = node / HBIN;
    int j = node - range * HBIN;
    const int* p = pcnt + ((size_t)(arr * 4 + range) * HSUB) * HBIN + j;
    int s = 0;
    #pragma unroll
    for (int k = 0; k < HSUB; ++k) s += p[(size_t)k * HBIN];
    cnt[g] = s;
}

// ------------------------------------------------- 3-phase scan over in-degrees (2NN)
__global__ void k_scan_blk(const int* __restrict__ cnt, int* __restrict__ off,
                           int* __restrict__ btot) {
    __shared__ int wsum[4];
    int tid = threadIdx.x, lane = tid & 63, wid = tid >> 6;
    int i = blockIdx.x * 256 + tid;
    int v = 0;
    if (i < 2 * NN) v = (i < NN) ? cnt[NN + i] : cnt[2 * NN + i];
    int s = v;
    #pragma unroll
    for (int o = 1; o < 64; o <<= 1) {
        int t = __shfl_up(s, o, 64);
        if (lane >= o) s += t;
    }
    if (lane == 63) wsum[wid] = s;
    __syncthreads();
    if (tid == 0) {
        int a = 0;
        #pragma unroll
        for (int w2 = 0; w2 < 4; ++w2) { int t = wsum[w2]; wsum[w2] = a; a += t; }
        btot[blockIdx.x] = a;
    }
    __syncthreads();
    if (i < 2 * NN) off[i] = wsum[wid] + s - v;
}

__global__ void k_scan_tops(const int* __restrict__ btot, int* __restrict__ bbase,
                            int* __restrict__ off) {
    __shared__ int wsum[8];
    int tid = threadIdx.x, lane = tid & 63, wid = tid >> 6;
    int v = (tid < NB2) ? btot[tid] : 0;
    int s = v;
    #pragma unroll
    for (int o = 1; o < 64; o <<= 1) {
        int t = __shfl_up(s, o, 64);
        if (lane >= o) s += t;
    }
    if (lane == 63) wsum[wid] = s;
    __syncthreads();
    if (tid == 0) {
        int a = 0;
        #pragma unroll
        for (int w2 = 0; w2 < 8; ++w2) { int t = wsum[w2]; wsum[w2] = a; a += t; }
        off[2 * NN] = a;
    }
    __syncthreads();
    if (tid < NB2) bbase[tid] = wsum[wid] + s - v;
}

// fixup + norms (both graphs) + cur copy
__global__ void k_scan_fin(int* __restrict__ off, const int* __restrict__ bbase,
                           int* __restrict__ cur, const int* __restrict__ cnt,
                           float* __restrict__ ns, float* __restrict__ nd) {
    int i = blockIdx.x * blockDim.x + threadIdx.x;
    if (i >= 2 * NN) return;
    int o = off[i] + bbase[i >> 8];
    off[i] = o;
    cur[i] = o;
    int co = (i < NN) ? cnt[i] : cnt[NN + i];          // out-degree
    int ci = (i < NN) ? cnt[NN + i] : cnt[2 * NN + i]; // in-degree
    ns[i] = 1.0f / sqrtf(fmaxf((float)co, 1.0f));
    nd[i] = 1.0f / sqrtf(fmaxf((float)ci, 1.0f));
}

// ------------------------------------------------- partitioned CSR fill
__global__ __launch_bounds__(256) void k_fill_part(
        const int* __restrict__ src_s, const int* __restrict__ dst_s,
        const int* __restrict__ src_t, const int* __restrict__ dst_t,
        int* __restrict__ cur, int* __restrict__ csr_src) {
    const int p = blockIdx.x & 7;
    const int blk = blockIdx.x >> 3;      // 0..NFB-1
    const unsigned lo = p * PSZ;
    for (int e = blk * 256 + (int)threadIdx.x; e < 2 * EE; e += NFB * 256) {
        int node, sv;
        if (e < EE) {
            node = dst_s[e];
            sv = src_s[e];
        } else {
            node = NN + dst_t[e - EE];
            sv = src_t[e - EE];
        }
        if ((unsigned)(node - lo) < (unsigned)PSZ) {
            int pos = atomicAdd(&cur[node], 1);
            csr_src[pos] = sv;
        }
    }
}

// ---------------------------------------------------------------- MFMA GEMM
// BM=128, BN=256. y2 output in grouped layout [8][NN][32].
template<int K, bool F32A>
__global__ __launch_bounds__(256, 2) void k_gemm(
        const void* __restrict__ Ap, const ushort* __restrict__ Bt,
        const float* __restrict__ ns, ushort* __restrict__ y2) {
    __shared__ ushort As[128 * 64];
    __shared__ ushort Bs[256 * 64];
    const int m0 = blockIdx.x * 128;
    const int t = threadIdx.x;
    const int wid = t >> 6, lane = t & 63;
    const int wr = (wid & 1) * 64;
    const int wc = (wid >> 1) * 128;
    const int l15 = lane & 15, lg = lane >> 4;

    f32x4 acc[4][8];
    #pragma unroll
    for (int m = 0; m < 4; ++m)
        #pragma unroll
        for (int n = 0; n < 8; ++n)
            acc[m][n] = {0.f, 0.f, 0.f, 0.f};

    const int srow = t >> 3;
    const int schunk = t & 7;

    for (int k0 = 0; k0 < K; k0 += 64) {
        #pragma unroll
        for (int i = 0; i < 4; ++i) {        // A tile 128x64
            int row = srow + i * 32;
            int sw = ((schunk ^ (row & 7)) * 8);
            int m = m0 + row; if (m >= NN) m = NN - 1;
            uint4 va;
            if constexpr (F32A) {
                const float* ap = (const float*)Ap + (size_t)m * K + k0 + schunk * 8;
                float4 f0 = *reinterpret_cast<const float4*>(ap);
                float4 f1 = *reinterpret_cast<const float4*>(ap + 4);
                va.x = (unsigned)f2bf(f0.x) | ((unsigned)f2bf(f0.y) << 16);
                va.y = (unsigned)f2bf(f0.z) | ((unsigned)f2bf(f0.w) << 16);
                va.z = (unsigned)f2bf(f1.x) | ((unsigned)f2bf(f1.y) << 16);
                va.w = (unsigned)f2bf(f1.z) | ((unsigned)f2bf(f1.w) << 16);
            } else {
                va = *reinterpret_cast<const uint4*>((const ushort*)Ap + (size_t)m * K + k0 + schunk * 8);
            }
            *reinterpret_cast<uint4*>(&As[row * 64 + sw]) = va;
        }
        #pragma unroll
        for (int i = 0; i < 8; ++i) {        // B tile 256x64
            int row = srow + i * 32;
            int sw = ((schunk ^ (row & 7)) * 8);
            uint4 vb = *reinterpret_cast<const uint4*>(&Bt[(size_t)row * K + k0 + schunk * 8]);
            *reinterpret_cast<uint4*>(&Bs[row * 64 + sw]) = vb;
        }
        __syncthreads();
        #pragma unroll
        for (int kk = 0; kk < 64; kk += 32) {
            const int kc = kk >> 3;
            bfrag af[4];
            #pragma unroll
            for (int m = 0; m < 4; ++m) {
                int row = wr + m * 16 + l15;
                af[m] = *reinterpret_cast<const bfrag*>(&As[row * 64 + (((lg + kc) ^ (row & 7)) * 8)]);
            }
            #pragma unroll
            for (int n = 0; n < 8; ++n) {
                int row = wc + n * 16 + l15;
                bfrag bg = *reinterpret_cast<const bfrag*>(&Bs[row * 64 + (((lg + kc) ^ (row & 7)) * 8)]);
                #pragma unroll
                for (int m = 0; m < 4; ++m)
                    acc[m][n] = __builtin_amdgcn_mfma_f32_16x16x32_bf16(af[m], bg, acc[m][n], 0, 0, 0);
            }
        }
        __syncthreads();
    }
    #pragma unroll
    for (int m = 0; m < 4; ++m) {
        #pragma unroll
        for (int r = 0; r < 4; ++r) {
            int row = m0 + wr + m * 16 + lg * 4 + r;
            if (row >= NN) continue;
            float nsv = ns[row];
            #pragma unroll
            for (int n = 0; n < 8; ++n) {
                int col = wc + n * 16 + l15;
                int grp = col >> 5, colw = col & 31;
                y2[(size_t)grp * NN * 32 + (size_t)row * 32 + colw] = f2bf(acc[m][n][r] * nsv);
            }
        }
    }
}

// ------------------------------------------------- SpMM: LDS-staged indices
__device__ inline void add8(float* a, uint4 v) {
    a[0] += __builtin_bit_cast(float, v.x << 16);
    a[1] += __builtin_bit_cast(float, v.x & 0xffff0000u);
    a[2] += __builtin_bit_cast(float, v.y << 16);
    a[3] += __builtin_bit_cast(float, v.y & 0xffff0000u);
    a[4] += __builtin_bit_cast(float, v.z << 16);
    a[5] += __builtin_bit_cast(float, v.z & 0xffff0000u);
    a[6] += __builtin_bit_cast(float, v.w << 16);
    a[7] += __builtin_bit_cast(float, v.w & 0xffff0000u);
}

#define SCAP 1536

__global__ __launch_bounds__(256) void k_spmm5(
        const ushort* __restrict__ y2, const int* __restrict__ off,
        const int* __restrict__ csr_src, const float* __restrict__ nd_arr,
        const float* __restrict__ bias, ushort* __restrict__ h_out) {
    __shared__ int sidx[4][SCAP];
    const int grp = blockIdx.x & 7;
    const int blk = blockIdx.x >> 3;          // 0..199
    const int tid = threadIdx.x;
    const int lane = tid & 63, wid = tid >> 6;
    const int slot = lane >> 2;               // 0..15
    const int sub = lane & 3;                 // 16B sub-chunk of the 32-col slice
    const ushort* ybase = y2 + (size_t)grp * NN * 32 + sub * 8;

    const int nb = (blk * 4 + wid) * 64;
    int s_wave0 = 0, cnt = 0;
    if (nb < NN) {
        int nend = nb + 64 < NN ? nb + 64 : NN;
        s_wave0 = off[nb];
        cnt = off[nend] - s_wave0;
    }
    int stage = cnt < SCAP ? cnt : SCAP;
    for (int j = lane; j < stage; j += 64)
        sidx[wid][j] = csr_src[s_wave0 + j];
    __syncthreads();

    float bia[8];
    #pragma unroll
    for (int j = 0; j < 8; ++j) bia[j] = bias[grp * 32 + sub * 8 + j];

    int e[4], e1[4], nidx[4], idx[4];
    bool act[4];
    float a[4][8];
    #pragma unroll
    for (int c = 0; c < 4; ++c) {
        nidx[c] = nb + c * 16 + slot;
        bool v = nidx[c] < NN;
        e[c]  = v ? off[nidx[c]] - s_wave0 : 0;
        e1[c] = v ? off[nidx[c] + 1] - s_wave0 : 0;
        #pragma unroll
        for (int j = 0; j < 8; ++j) a[c][j] = 0.f;
        act[c] = e[c] < e1[c];
        if (act[c]) idx[c] = (e[c] < SCAP) ? sidx[wid][e[c]] : csr_src[s_wave0 + e[c]];
    }

    while (act[0] | act[1] | act[2] | act[3]) {
        uint4 v[4];
        bool ca[4];
        #pragma unroll
        for (int c = 0; c < 4; ++c) {
            ca[c] = act[c];
            if (ca[c]) v[c] = *reinterpret_cast<const uint4*>(&ybase[(size_t)idx[c] * 32]);
        }
        #pragma unroll
        for (int c = 0; c < 4; ++c) {
            if (ca[c]) ++e[c];
            act[c] = e[c] < e1[c];
            if (act[c]) idx[c] = (e[c] < SCAP) ? sidx[wid][e[c]] : csr_src[s_wave0 + e[c]];
        }
        #pragma unroll
        for (int c = 0; c < 4; ++c)
            if (ca[c]) add8(a[c], v[c]);
    }

    #pragma unroll
    for (int c = 0; c < 4; ++c) {
        int n = nidx[c];
        if (n >= NN) continue;
        float nd = nd_arr[n];
        ushort r[8];
        #pragma unroll
        for (int j = 0; j < 8; ++j) r[j] = f2bf(fmaxf(a[c][j] * nd + bia[j], 0.f));
        uint4 pk;
        pk.x = (unsigned)r[0] | ((unsigned)r[1] << 16);
        pk.y = (unsigned)r[2] | ((unsigned)r[3] << 16);
        pk.z = (unsigned)r[4] | ((unsigned)r[5] << 16);
        pk.w = (unsigned)r[6] | ((unsigned)r[7] << 16);
        *reinterpret_cast<uint4*>(&h_out[(size_t)n * 256 + grp * 32 + sub * 8]) = pk;
    }
}

// ------------------------------------------------- MFMA tail: fc + dlog + losses
__global__ __launch_bounds__(256) void k_tail_mfma(
        const ushort* __restrict__ h0, const ushort* __restrict__ h1,
        const ushort* __restrict__ Wt1, const ushort* __restrict__ Wt2,
        const float* __restrict__ bfc, const float* __restrict__ bd,
        const int* __restrict__ labels, int g,
        float* __restrict__ pcls, float* __restrict__ pdom) {
    __shared__ float sT1[4][16][17];
    __shared__ float sT2[4][16][17];
    __shared__ float sc[4], sd[4];
    const int tid = threadIdx.x;
    const int wid = tid >> 6, lane = tid & 63;
    const int l15 = lane & 15, lg = lane >> 4;
    const int base = blockIdx.x * 64 + wid * 16;

    int arow = base + l15; if (arow >= NN) arow = NN - 1;
    const ushort* a1 = h1 + (size_t)arow * 256 + lg * 8;
    const ushort* a0 = h0 + (size_t)arow * 256 + lg * 8;
    const ushort* b1 = Wt1 + (size_t)l15 * 256 + lg * 8;
    const ushort* b2 = Wt2 + (size_t)l15 * 256 + lg * 8;
    f32x4 acc1 = {0.f, 0.f, 0.f, 0.f};
    f32x4 acc2 = {0.f, 0.f, 0.f, 0.f};
    #pragma unroll
    for (int kk = 0; kk < 8; ++kk) {
        bfrag af1 = *reinterpret_cast<const bfrag*>(a1 + kk * 32);
        bfrag bg1 = *reinterpret_cast<const bfrag*>(b1 + kk * 32);
        acc1 = __builtin_amdgcn_mfma_f32_16x16x32_bf16(af1, bg1, acc1, 0, 0, 0);
        bfrag af0 = *reinterpret_cast<const bfrag*>(a0 + kk * 32);
        bfrag bg2 = *reinterpret_cast<const bfrag*>(b2 + kk * 32);
        acc2 = __builtin_amdgcn_mfma_f32_16x16x32_bf16(af0, bg2, acc2, 0, 0, 0);
    }
    #pragma unroll
    for (int j = 0; j < 4; ++j) {
        sT1[wid][lg * 4 + j][l15] = acc1[j];
        sT2[wid][lg * 4 + j][l15] = acc2[j];
    }
    __syncthreads();

    float cls = 0.f, dom = 0.f;
    int n = base + lane;
    if (lane < 16 && n < NN) {
        float lgt[10];
        #pragma unroll
        for (int c = 0; c < 10; ++c) lgt[c] = sT1[wid][lane][c] + bfc[c];
        float dl0 = bd[0] + sT2[wid][lane][0] + sT1[wid][lane][10];
        float dl1 = bd[1] + sT2[wid][lane][1] + sT1[wid][lane][11];
        if (g == 0) {
            float m = lgt[0];
            #pragma unroll
            for (int c = 1; c < 10; ++c) m = fmaxf(m, lgt[c]);
            float s = 0.f;
            #pragma unroll
            for (int c = 0; c < 10; ++c) s += expf(lgt[c] - m);
            int lab = labels[n];
            float tgt = lgt[0];
            #pragma unroll
            for (int c = 1; c < 10; ++c) tgt = (c == lab) ? lgt[c] : tgt;
            cls = -(tgt - (m + logf(s)));
        }
        float m2 = fmaxf(dl0, dl1);
        float lse2 = m2 + logf(expf(dl0 - m2) + expf(dl1 - m2));
        dom = -((g ? dl1 : dl0) - lse2);
    }
    #pragma unroll
    for (int o = 1; o < 16; o <<= 1) {
        cls += __shfl_xor(cls, o, 64);
        dom += __shfl_xor(dom, o, 64);
    }
    if (lane == 0) { sc[wid] = cls; sd[wid] = dom; }
    __syncthreads();
    if (tid == 0) {
        float c = sc[0] + sc[1] + sc[2] + sc[3];
        float d = sd[0] + sd[1] + sd[2] + sd[3];
        if (g == 0) pcls[blockIdx.x] = c;
        pdom[g * NTB + blockIdx.x] = d;
    }
}

__global__ void k_finalize(const float* __restrict__ pcls, const float* __restrict__ pdom,
                           float* __restrict__ out) {
    __shared__ float sc[4], sd[4];
    int tid = threadIdx.x, lane = tid & 63, wid = tid >> 6;
    float c = 0.f, d = 0.f;
    for (int i = tid; i < NTB; i += 256) c += pcls[i];
    for (int i = tid; i < 2 * NTB; i += 256) d += pdom[i];
    #pragma unroll
    for (int o = 32; o; o >>= 1) {
        c += __shfl_xor(c, o, 64);
        d += __shfl_xor(d, o, 64);
    }
    if (lane == 0) { sc[wid] = c; sd[wid] = d; }
    __syncthreads();
    if (tid == 0) {
        float ct = sc[0] + sc[1] + sc[2] + sc[3];
        float dt = sd[0] + sd[1] + sd[2] + sd[3];
        out[0] = ct / (float)NN + 0.01f * (dt / (float)(2 * NN));
    }
}

// ---------------------------------------------------------------- launch
extern "C" void kernel_launch(void* const* d_in, const int* in_sizes, int n_in,
                              void* d_out, int out_size, void* d_ws, size_t ws_size,
                              hipStream_t stream) {
    const float* features_s = (const float*)d_in[0];
    const int*   labels_s   = (const int*)d_in[1];
    const float* features_t = (const float*)d_in[2];
    const int*   src_s      = (const int*)d_in[3];
    const int*   dst_s      = (const int*)d_in[4];
    const int*   src_t      = (const int*)d_in[5];
    const int*   dst_t      = (const int*)d_in[6];
    const float* W0         = (const float*)d_in[7];
    const float* b0         = (const float*)d_in[8];
    const float* W1         = (const float*)d_in[9];
    const float* b1         = (const float*)d_in[10];
    const float* Wfc        = (const float*)d_in[11];
    const float* bfc        = (const float*)d_in[12];
    const float* Wd         = (const float*)d_in[13];
    const float* bd         = (const float*)d_in[14];
    float* out = (float*)d_out;

    auto align256 = [](size_t x) { return (x + 255) & ~(size_t)255; };
    char* w = (char*)d_ws;
    ushort* h0     = (ushort*)w; w += align256((size_t)NN * HH * 2);     // 25.6 MB
    ushort* h1     = (ushort*)w; w += align256((size_t)NN * HH * 2);     // 25.6 MB
    ushort* y2     = (ushort*)w; w += align256((size_t)NN * HH * 2);     // 25.6 MB grouped
    ushort* W0t    = (ushort*)w; w += align256((size_t)INF * HH * 2);
    ushort* W1t    = (ushort*)w; w += align256((size_t)HH * HH * 2);
    ushort* Wt1    = (ushort*)w; w += align256((size_t)16 * HH * 2);
    ushort* Wt2    = (ushort*)w; w += align256((size_t)16 * HH * 2);
    float* ns      = (float*)w;  w += align256((size_t)2 * NN * 4);
    float* nd      = (float*)w;  w += align256((size_t)2 * NN * 4);
    int*   cnt     = (int*)w;    w += align256((size_t)4 * NN * 4);
    int*   csr_off = (int*)w;    w += align256((size_t)(2 * NN + 1) * 4);
    int*   csr_cur = (int*)w;    w += align256((size_t)2 * NN * 4);
    int*   csr_src = (int*)w;    w += align256((size_t)2 * EE * 4);      // 6.4 MB
    int*   btot    = (int*)w;    w += align256((size_t)NB2 * 4);
    int*   bbase   = (int*)w;    w += align256((size_t)NB2 * 4);
    float* pcls    = (float*)w;  w += align256((size_t)NTB * 4);
    float* pdom    = (float*)w;  w += align256((size_t)2 * NTB * 4);
    int*   pcnt    = (int*)w;    w += align256((size_t)16 * HSUB * HBIN * 4); // 12.8 MB

    const int TB = 256;
    k_cast_wt<INF><<<(INF * HH + TB - 1) / TB, TB, 0, stream>>>(W0, W0t);
    k_cast_wt<HH><<<(HH * HH + TB - 1) / TB, TB, 0, stream>>>(W1, W1t);
    k_cast_wtail<<<(16 * HH + TB - 1) / TB, TB, 0, stream>>>(Wfc, Wd, Wt1);
    k_cast_wtail2<<<(16 * HH + TB - 1) / TB, TB, 0, stream>>>(Wd, Wt2);

    // batched CSR prep for both graphs (LDS-histogram degrees, no global atomics)
    k_deghist<<<16 * HSUB, TB, 0, stream>>>(src_s, dst_s, src_t, dst_t, pcnt);
    k_degsum<<<(4 * NN + TB - 1) / TB, TB, 0, stream>>>(pcnt, cnt);
    k_scan_blk<<<NB2, TB, 0, stream>>>(cnt, csr_off, btot);
    k_scan_tops<<<1, 512, 0, stream>>>(btot, bbase, csr_off);
    k_scan_fin<<<NB2, TB, 0, stream>>>(csr_off, bbase, csr_cur, cnt, ns, nd);
    k_fill_part<<<NFB * 8, TB, 0, stream>>>(src_s, dst_s, src_t, dst_t,
                                            csr_cur, csr_src);

    const int GB = (NN + 127) / 128;   // 391
    for (int g = 0; g < 2; ++g) {
        const float* feats = g ? features_t : features_s;
        const int*   offg  = csr_off + (size_t)g * NN;
        const float* nsg   = ns + (size_t)g * NN;
        const float* ndg   = nd + (size_t)g * NN;

        k_gemm<INF, true><<<GB, TB, 0, stream>>>(feats, W0t, nsg, y2);
        k_spmm5<<<SPMM_BLOCKS, TB, 0, stream>>>(y2, offg, csr_src, ndg, b0, h0);
        k_gemm<HH, false><<<GB, TB, 0, stream>>>(h0, W1t, nsg, y2);
        k_spmm5<<<SPMM_BLOCKS, TB, 0, stream>>>(y2, offg, csr_src, ndg, b1, h1);
        k_tail_mfma<<<NTB, TB, 0, stream>>>(h0, h1, Wt1, Wt2, bfc, bd, labels_s, g,
                                            pcls, pdom);
    }
    k_finalize<<<1, TB, 0, stream>>>(pcls, pdom, out);
}

// Round 10
// 567.620 us; speedup vs baseline: 2.4183x; 1.0858x over previous
//
#include <hip/hip_runtime.h>
#include <cstdint>
#include <cstddef>

#define NN 50000
#define EE 800000
#define INF 512
#define HH  256
#define CC  10
#define NB2 391            // ceil(2*NN/256) scan blocks
#define NTB 782            // ceil(NN/64)  tail blocks
#define SPMM_BLOCKS 1600   // 200 blocks per column group x 8 groups
#define NFB 104            // fill blocks per partition
#define PSZ 12500          // nodes per fill partition (2*NN/8)
#define HBIN 6250          // histogram bins per range task (25KB LDS)
#define HRNG 8             // ranges per array (8*6250 = NN)
#define HSUB 32            // sub-blocks per task

using bfrag = __attribute__((ext_vector_type(8))) __bf16;
using f32x4 = __attribute__((ext_vector_type(4))) float;

__device__ inline unsigned short f2bf(float x) {
    unsigned u = __builtin_bit_cast(unsigned, x);
    unsigned r = u + 0x7FFFu + ((u >> 16) & 1u);
    return (unsigned short)(r >> 16);
}
__device__ inline float bf2f(unsigned short h) {
    return __builtin_bit_cast(float, (unsigned)h << 16);
}

// ---------------------------------------------------------------- weight casts
template<int K>
__global__ void k_cast_wt(const float* __restrict__ W, ushort* __restrict__ Wt) {
    int idx = blockIdx.x * blockDim.x + threadIdx.x;
    if (idx >= K * HH) return;
    int n = idx / K, k = idx % K;
    Wt[idx] = f2bf(W[(size_t)k * HH + n]);
}

__global__ void k_cast_wtail(const float* __restrict__ Wfc, const float* __restrict__ Wd,
                             ushort* __restrict__ Wt1) {
    int idx = blockIdx.x * blockDim.x + threadIdx.x;
    if (idx >= 16 * HH) return;
    int n = idx >> 8, k = idx & 255;
    float v = 0.f;
    if (n < 10)       v = Wfc[(size_t)k * 10 + n];
    else if (n < 12)  v = Wd[(size_t)(HH + k) * 2 + (n - 10)];
    Wt1[idx] = f2bf(v);
}

__global__ void k_cast_wtail2(const float* __restrict__ Wd, ushort* __restrict__ Wt2) {
    int idx = blockIdx.x * blockDim.x + threadIdx.x;
    if (idx >= 16 * HH) return;
    int n = idx >> 8, k = idx & 255;
    float v = (n < 2) ? Wd[(size_t)k * 2 + n] : 0.f;
    Wt2[idx] = f2bf(v);
}

// ---------------------------------------------------------------- LDS histogram degrees
// task = arr(4) x range(8); HSUB blocks per task; int4-vectorized edge reads.
// Partials as ushort (max per sub-block = EE/HSUB = 25000 < 65536).
__global__ __launch_bounds__(256) void k_deghist(
        const int* __restrict__ src_s, const int* __restrict__ dst_s,
        const int* __restrict__ src_t, const int* __restrict__ dst_t,
        ushort* __restrict__ pcnt) {
    __shared__ int hist[HBIN];
    const int task = blockIdx.x >> 5;    // 0..31
    const int sub  = blockIdx.x & 31;    // 0..31
    const int arr = task >> 3, range = task & 7;
    const int* p = (arr == 0) ? src_s : (arr == 1) ? dst_s : (arr == 2) ? src_t : dst_t;
    const int4* p4 = reinterpret_cast<const int4*>(p);
    const int lo = range * HBIN;
    for (int j = threadIdx.x; j < HBIN; j += 256) hist[j] = 0;
    __syncthreads();
    for (int i = sub * 256 + (int)threadIdx.x; i < EE / 4; i += HSUB * 256) {
        int4 v = p4[i];
        int a0 = v.x - lo, a1 = v.y - lo, a2 = v.z - lo, a3 = v.w - lo;
        if ((unsigned)a0 < (unsigned)HBIN) atomicAdd(&hist[a0], 1);
        if ((unsigned)a1 < (unsigned)HBIN) atomicAdd(&hist[a1], 1);
        if ((unsigned)a2 < (unsigned)HBIN) atomicAdd(&hist[a2], 1);
        if ((unsigned)a3 < (unsigned)HBIN) atomicAdd(&hist[a3], 1);
    }
    __syncthreads();
    ushort* out = pcnt + ((size_t)task * HSUB + sub) * HBIN;
    for (int j = threadIdx.x; j < HBIN; j += 256) out[j] = (ushort)hist[j];
}

// sum the HSUB partials -> cnt [out_s][in_s][out_t][in_t]
__global__ void k_degsum(const ushort* __restrict__ pcnt, int* __restrict__ cnt) {
    int g = blockIdx.x * blockDim.x + threadIdx.x;
    if (g >= 4 * NN) return;
    int arr = g / NN;
    int node = g - arr * NN;
    int range = node / HBIN;
    int j = node - range * HBIN;
    const ushort* p = pcnt + ((size_t)(arr * HRNG + range) * HSUB) * HBIN + j;
    int s = 0;
    #pragma unroll
    for (int k = 0; k < HSUB; ++k) s += p[(size_t)k * HBIN];
    cnt[g] = s;
}

// ------------------------------------------------- 3-phase scan over in-degrees (2NN)
__global__ void k_scan_blk(const int* __restrict__ cnt, int* __restrict__ off,
                           int* __restrict__ btot) {
    __shared__ int wsum[4];
    int tid = threadIdx.x, lane = tid & 63, wid = tid >> 6;
    int i = blockIdx.x * 256 + tid;
    int v = 0;
    if (i < 2 * NN) v = (i < NN) ? cnt[NN + i] : cnt[2 * NN + i];
    int s = v;
    #pragma unroll
    for (int o = 1; o < 64; o <<= 1) {
        int t = __shfl_up(s, o, 64);
        if (lane >= o) s += t;
    }
    if (lane == 63) wsum[wid] = s;
    __syncthreads();
    if (tid == 0) {
        int a = 0;
        #pragma unroll
        for (int w2 = 0; w2 < 4; ++w2) { int t = wsum[w2]; wsum[w2] = a; a += t; }
        btot[blockIdx.x] = a;
    }
    __syncthreads();
    if (i < 2 * NN) off[i] = wsum[wid] + s - v;
}

__global__ void k_scan_tops(const int* __restrict__ btot, int* __restrict__ bbase,
                            int* __restrict__ off) {
    __shared__ int wsum[8];
    int tid = threadIdx.x, lane = tid & 63, wid = tid >> 6;
    int v = (tid < NB2) ? btot[tid] : 0;
    int s = v;
    #pragma unroll
    for (int o = 1; o < 64; o <<= 1) {
        int t = __shfl_up(s, o, 64);
        if (lane >= o) s += t;
    }
    if (lane == 63) wsum[wid] = s;
    __syncthreads();
    if (tid == 0) {
        int a = 0;
        #pragma unroll
        for (int w2 = 0; w2 < 8; ++w2) { int t = wsum[w2]; wsum[w2] = a; a += t; }
        off[2 * NN] = a;
    }
    __syncthreads();
    if (tid < NB2) bbase[tid] = wsum[wid] + s - v;
}

// fixup + norms (both graphs) + cur copy
__global__ void k_scan_fin(int* __restrict__ off, const int* __restrict__ bbase,
                           int* __restrict__ cur, const int* __restrict__ cnt,
                           float* __restrict__ ns, float* __restrict__ nd) {
    int i = blockIdx.x * blockDim.x + threadIdx.x;
    if (i >= 2 * NN) return;
    int o = off[i] + bbase[i >> 8];
    off[i] = o;
    cur[i] = o;
    int co = (i < NN) ? cnt[i] : cnt[NN + i];          // out-degree
    int ci = (i < NN) ? cnt[NN + i] : cnt[2 * NN + i]; // in-degree
    ns[i] = 1.0f / sqrtf(fmaxf((float)co, 1.0f));
    nd[i] = 1.0f / sqrtf(fmaxf((float)ci, 1.0f));
}

// ------------------------------------------------- partitioned CSR fill
// src loaded only for owned edges (1/8) -> ~64MB reads instead of 102MB.
__global__ __launch_bounds__(256) void k_fill_part(
        const int* __restrict__ src_s, const int* __restrict__ dst_s,
        const int* __restrict__ src_t, const int* __restrict__ dst_t,
        int* __restrict__ cur, int* __restrict__ csr_src) {
    const int p = blockIdx.x & 7;
    const int blk = blockIdx.x >> 3;      // 0..NFB-1
    const unsigned lo = p * PSZ;
    for (int e = blk * 256 + (int)threadIdx.x; e < 2 * EE; e += NFB * 256) {
        int node;
        if (e < EE) node = dst_s[e];
        else        node = NN + dst_t[e - EE];
        if ((unsigned)(node - lo) < (unsigned)PSZ) {
            int sv = (e < EE) ? src_s[e] : src_t[e - EE];
            int pos = atomicAdd(&cur[node], 1);
            csr_src[pos] = sv;
        }
    }
}

// ---------------------------------------------------------------- MFMA GEMM
// BM=128, BN=256. y2 output in grouped layout [8][NN][32].
template<int K, bool F32A>
__global__ __launch_bounds__(256, 2) void k_gemm(
        const void* __restrict__ Ap, const ushort* __restrict__ Bt,
        const float* __restrict__ ns, ushort* __restrict__ y2) {
    __shared__ ushort As[128 * 64];
    __shared__ ushort Bs[256 * 64];
    const int m0 = blockIdx.x * 128;
    const int t = threadIdx.x;
    const int wid = t >> 6, lane = t & 63;
    const int wr = (wid & 1) * 64;
    const int wc = (wid >> 1) * 128;
    const int l15 = lane & 15, lg = lane >> 4;

    f32x4 acc[4][8];
    #pragma unroll
    for (int m = 0; m < 4; ++m)
        #pragma unroll
        for (int n = 0; n < 8; ++n)
            acc[m][n] = {0.f, 0.f, 0.f, 0.f};

    const int srow = t >> 3;
    const int schunk = t & 7;

    for (int k0 = 0; k0 < K; k0 += 64) {
        #pragma unroll
        for (int i = 0; i < 4; ++i) {        // A tile 128x64
            int row = srow + i * 32;
            int sw = ((schunk ^ (row & 7)) * 8);
            int m = m0 + row; if (m >= NN) m = NN - 1;
            uint4 va;
            if constexpr (F32A) {
                const float* ap = (const float*)Ap + (size_t)m * K + k0 + schunk * 8;
                float4 f0 = *reinterpret_cast<const float4*>(ap);
                float4 f1 = *reinterpret_cast<const float4*>(ap + 4);
                va.x = (unsigned)f2bf(f0.x) | ((unsigned)f2bf(f0.y) << 16);
                va.y = (unsigned)f2bf(f0.z) | ((unsigned)f2bf(f0.w) << 16);
                va.z = (unsigned)f2bf(f1.x) | ((unsigned)f2bf(f1.y) << 16);
                va.w = (unsigned)f2bf(f1.z) | ((unsigned)f2bf(f1.w) << 16);
            } else {
                va = *reinterpret_cast<const uint4*>((const ushort*)Ap + (size_t)m * K + k0 + schunk * 8);
            }
            *reinterpret_cast<uint4*>(&As[row * 64 + sw]) = va;
        }
        #pragma unroll
        for (int i = 0; i < 8; ++i) {        // B tile 256x64
            int row = srow + i * 32;
            int sw = ((schunk ^ (row & 7)) * 8);
            uint4 vb = *reinterpret_cast<const uint4*>(&Bt[(size_t)row * K + k0 + schunk * 8]);
            *reinterpret_cast<uint4*>(&Bs[row * 64 + sw]) = vb;
        }
        __syncthreads();
        #pragma unroll
        for (int kk = 0; kk < 64; kk += 32) {
            const int kc = kk >> 3;
            bfrag af[4];
            #pragma unroll
            for (int m = 0; m < 4; ++m) {
                int row = wr + m * 16 + l15;
                af[m] = *reinterpret_cast<const bfrag*>(&As[row * 64 + (((lg + kc) ^ (row & 7)) * 8)]);
            }
            #pragma unroll
            for (int n = 0; n < 8; ++n) {
                int row = wc + n * 16 + l15;
                bfrag bg = *reinterpret_cast<const bfrag*>(&Bs[row * 64 + (((lg + kc) ^ (row & 7)) * 8)]);
                #pragma unroll
                for (int m = 0; m < 4; ++m)
                    acc[m][n] = __builtin_amdgcn_mfma_f32_16x16x32_bf16(af[m], bg, acc[m][n], 0, 0, 0);
            }
        }
        __syncthreads();
    }
    #pragma unroll
    for (int m = 0; m < 4; ++m) {
        #pragma unroll
        for (int r = 0; r < 4; ++r) {
            int row = m0 + wr + m * 16 + lg * 4 + r;
            if (row >= NN) continue;
            float nsv = ns[row];
            #pragma unroll
            for (int n = 0; n < 8; ++n) {
                int col = wc + n * 16 + l15;
                int grp = col >> 5, colw = col & 31;
                y2[(size_t)grp * NN * 32 + (size_t)row * 32 + colw] = f2bf(acc[m][n][r] * nsv);
            }
        }
    }
}

// ------------------------------------------------- SpMM: LDS-staged indices
__device__ inline void add8(float* a, uint4 v) {
    a[0] += __builtin_bit_cast(float, v.x << 16);
    a[1] += __builtin_bit_cast(float, v.x & 0xffff0000u);
    a[2] += __builtin_bit_cast(float, v.y << 16);
    a[3] += __builtin_bit_cast(float, v.y & 0xffff0000u);
    a[4] += __builtin_bit_cast(float, v.z << 16);
    a[5] += __builtin_bit_cast(float, v.z & 0xffff0000u);
    a[6] += __builtin_bit_cast(float, v.w << 16);
    a[7] += __builtin_bit_cast(float, v.w & 0xffff0000u);
}

#define SCAP 1536

__global__ __launch_bounds__(256) void k_spmm5(
        const ushort* __restrict__ y2, const int* __restrict__ off,
        const int* __restrict__ csr_src, const float* __restrict__ nd_arr,
        const float* __restrict__ bias, ushort* __restrict__ h_out) {
    __shared__ int sidx[4][SCAP];
    const int grp = blockIdx.x & 7;
    const int blk = blockIdx.x >> 3;          // 0..199
    const int tid = threadIdx.x;
    const int lane = tid & 63, wid = tid >> 6;
    const int slot = lane >> 2;               // 0..15
    const int sub = lane & 3;                 // 16B sub-chunk of the 32-col slice
    const ushort* ybase = y2 + (size_t)grp * NN * 32 + sub * 8;

    const int nb = (blk * 4 + wid) * 64;
    int s_wave0 = 0, cnt = 0;
    if (nb < NN) {
        int nend = nb + 64 < NN ? nb + 64 : NN;
        s_wave0 = off[nb];
        cnt = off[nend] - s_wave0;
    }
    int stage = cnt < SCAP ? cnt : SCAP;
    for (int j = lane; j < stage; j += 64)
        sidx[wid][j] = csr_src[s_wave0 + j];
    __syncthreads();

    float bia[8];
    #pragma unroll
    for (int j = 0; j < 8; ++j) bia[j] = bias[grp * 32 + sub * 8 + j];

    int e[4], e1[4], nidx[4], idx[4];
    bool act[4];
    float a[4][8];
    #pragma unroll
    for (int c = 0; c < 4; ++c) {
        nidx[c] = nb + c * 16 + slot;
        bool v = nidx[c] < NN;
        e[c]  = v ? off[nidx[c]] - s_wave0 : 0;
        e1[c] = v ? off[nidx[c] + 1] - s_wave0 : 0;
        #pragma unroll
        for (int j = 0; j < 8; ++j) a[c][j] = 0.f;
        act[c] = e[c] < e1[c];
        if (act[c]) idx[c] = (e[c] < SCAP) ? sidx[wid][e[c]] : csr_src[s_wave0 + e[c]];
    }

    while (act[0] | act[1] | act[2] | act[3]) {
        uint4 v[4];
        bool ca[4];
        #pragma unroll
        for (int c = 0; c < 4; ++c) {
            ca[c] = act[c];
            if (ca[c]) v[c] = *reinterpret_cast<const uint4*>(&ybase[(size_t)idx[c] * 32]);
        }
        #pragma unroll
        for (int c = 0; c < 4; ++c) {
            if (ca[c]) ++e[c];
            act[c] = e[c] < e1[c];
            if (act[c]) idx[c] = (e[c] < SCAP) ? sidx[wid][e[c]] : csr_src[s_wave0 + e[c]];
        }
        #pragma unroll
        for (int c = 0; c < 4; ++c)
            if (ca[c]) add8(a[c], v[c]);
    }

    #pragma unroll
    for (int c = 0; c < 4; ++c) {
        int n = nidx[c];
        if (n >= NN) continue;
        float nd = nd_arr[n];
        ushort r[8];
        #pragma unroll
        for (int j = 0; j < 8; ++j) r[j] = f2bf(fmaxf(a[c][j] * nd + bia[j], 0.f));
        uint4 pk;
        pk.x = (unsigned)r[0] | ((unsigned)r[1] << 16);
        pk.y = (unsigned)r[2] | ((unsigned)r[3] << 16);
        pk.z = (unsigned)r[4] | ((unsigned)r[5] << 16);
        pk.w = (unsigned)r[6] | ((unsigned)r[7] << 16);
        *reinterpret_cast<uint4*>(&h_out[(size_t)n * 256 + grp * 32 + sub * 8]) = pk;
    }
}

// ------------------------------------------------- MFMA tail: fc + dlog + losses
__global__ __launch_bounds__(256) void k_tail_mfma(
        const ushort* __restrict__ h0, const ushort* __restrict__ h1,
        const ushort* __restrict__ Wt1, const ushort* __restrict__ Wt2,
        const float* __restrict__ bfc, const float* __restrict__ bd,
        const int* __restrict__ labels, int g,
        float* __restrict__ pcls, float* __restrict__ pdom) {
    __shared__ float sT1[4][16][17];
    __shared__ float sT2[4][16][17];
    __shared__ float sc[4], sd[4];
    const int tid = threadIdx.x;
    const int wid = tid >> 6, lane = tid & 63;
    const int l15 = lane & 15, lg = lane >> 4;
    const int base = blockIdx.x * 64 + wid * 16;

    int arow = base + l15; if (arow >= NN) arow = NN - 1;
    const ushort* a1 = h1 + (size_t)arow * 256 + lg * 8;
    const ushort* a0 = h0 + (size_t)arow * 256 + lg * 8;
    const ushort* b1 = Wt1 + (size_t)l15 * 256 + lg * 8;
    const ushort* b2 = Wt2 + (size_t)l15 * 256 + lg * 8;
    f32x4 acc1 = {0.f, 0.f, 0.f, 0.f};
    f32x4 acc2 = {0.f, 0.f, 0.f, 0.f};
    #pragma unroll
    for (int kk = 0; kk < 8; ++kk) {
        bfrag af1 = *reinterpret_cast<const bfrag*>(a1 + kk * 32);
        bfrag bg1 = *reinterpret_cast<const bfrag*>(b1 + kk * 32);
        acc1 = __builtin_amdgcn_mfma_f32_16x16x32_bf16(af1, bg1, acc1, 0, 0, 0);
        bfrag af0 = *reinterpret_cast<const bfrag*>(a0 + kk * 32);
        bfrag bg2 = *reinterpret_cast<const bfrag*>(b2 + kk * 32);
        acc2 = __builtin_amdgcn_mfma_f32_16x16x32_bf16(af0, bg2, acc2, 0, 0, 0);
    }
    #pragma unroll
    for (int j = 0; j < 4; ++j) {
        sT1[wid][lg * 4 + j][l15] = acc1[j];
        sT2[wid][lg * 4 + j][l15] = acc2[j];
    }
    __syncthreads();

    float cls = 0.f, dom = 0.f;
    int n = base + lane;
    if (lane < 16 && n < NN) {
        float lgt[10];
        #pragma unroll
        for (int c = 0; c < 10; ++c) lgt[c] = sT1[wid][lane][c] + bfc[c];
        float dl0 = bd[0] + sT2[wid][lane][0] + sT1[wid][lane][10];
        float dl1 = bd[1] + sT2[wid][lane][1] + sT1[wid][lane][11];
        if (g == 0) {
            float m = lgt[0];
            #pragma unroll
            for (int c = 1; c < 10; ++c) m = fmaxf(m, lgt[c]);
            float s = 0.f;
            #pragma unroll
            for (int c = 0; c < 10; ++c) s += expf(lgt[c] - m);
            int lab = labels[n];
            float tgt = lgt[0];
            #pragma unroll
            for (int c = 1; c < 10; ++c) tgt = (c == lab) ? lgt[c] : tgt;
            cls = -(tgt - (m + logf(s)));
        }
        float m2 = fmaxf(dl0, dl1);
        float lse2 = m2 + logf(expf(dl0 - m2) + expf(dl1 - m2));
        dom = -((g ? dl1 : dl0) - lse2);
    }
    #pragma unroll
    for (int o = 1; o < 16; o <<= 1) {
        cls += __shfl_xor(cls, o, 64);
        dom += __shfl_xor(dom, o, 64);
    }
    if (lane == 0) { sc[wid] = cls; sd[wid] = dom; }
    __syncthreads();
    if (tid == 0) {
        float c = sc[0] + sc[1] + sc[2] + sc[3];
        float d = sd[0] + sd[1] + sd[2] + sd[3];
        if (g == 0) pcls[blockIdx.x] = c;
        pdom[g * NTB + blockIdx.x] = d;
    }
}

__global__ void k_finalize(const float* __restrict__ pcls, const float* __restrict__ pdom,
                           float* __restrict__ out) {
    __shared__ float sc[4], sd[4];
    int tid = threadIdx.x, lane = tid & 63, wid = tid >> 6;
    float c = 0.f, d = 0.f;
    for (int i = tid; i < NTB; i += 256) c += pcls[i];
    for (int i = tid; i < 2 * NTB; i += 256) d += pdom[i];
    #pragma unroll
    for (int o = 32; o; o >>= 1) {
        c += __shfl_xor(c, o, 64);
        d += __shfl_xor(d, o, 64);
    }
    if (lane == 0) { sc[wid] = c; sd[wid] = d; }
    __syncthreads();
    if (tid == 0) {
        float ct = sc[0] + sc[1] + sc[2] + sc[3];
        float dt = sd[0] + sd[1] + sd[2] + sd[3];
        out[0] = ct / (float)NN + 0.01f * (dt / (float)(2 * NN));
    }
}

// ---------------------------------------------------------------- launch
extern "C" void kernel_launch(void* const* d_in, const int* in_sizes, int n_in,
                              void* d_out, int out_size, void* d_ws, size_t ws_size,
                              hipStream_t stream) {
    const float* features_s = (const float*)d_in[0];
    const int*   labels_s   = (const int*)d_in[1];
    const float* features_t = (const float*)d_in[2];
    const int*   src_s      = (const int*)d_in[3];
    const int*   dst_s      = (const int*)d_in[4];
    const int*   src_t      = (const int*)d_in[5];
    const int*   dst_t      = (const int*)d_in[6];
    const float* W0         = (const float*)d_in[7];
    const float* b0         = (const float*)d_in[8];
    const float* W1         = (const float*)d_in[9];
    const float* b1         = (const float*)d_in[10];
    const float* Wfc        = (const float*)d_in[11];
    const float* bfc        = (const float*)d_in[12];
    const float* Wd         = (const float*)d_in[13];
    const float* bd         = (const float*)d_in[14];
    float* out = (float*)d_out;

    auto align256 = [](size_t x) { return (x + 255) & ~(size_t)255; };
    char* w = (char*)d_ws;
    ushort* h0     = (ushort*)w; w += align256((size_t)NN * HH * 2);     // 25.6 MB
    ushort* h1     = (ushort*)w; w += align256((size_t)NN * HH * 2);     // 25.6 MB
    ushort* y2     = (ushort*)w; w += align256((size_t)NN * HH * 2);     // 25.6 MB grouped
    ushort* W0t    = (ushort*)w; w += align256((size_t)INF * HH * 2);
    ushort* W1t    = (ushort*)w; w += align256((size_t)HH * HH * 2);
    ushort* Wt1    = (ushort*)w; w += align256((size_t)16 * HH * 2);
    ushort* Wt2    = (ushort*)w; w += align256((size_t)16 * HH * 2);
    float* ns      = (float*)w;  w += align256((size_t)2 * NN * 4);
    float* nd      = (float*)w;  w += align256((size_t)2 * NN * 4);
    int*   cnt     = (int*)w;    w += align256((size_t)4 * NN * 4);
    int*   csr_off = (int*)w;    w += align256((size_t)(2 * NN + 1) * 4);
    int*   csr_cur = (int*)w;    w += align256((size_t)2 * NN * 4);
    int*   csr_src = (int*)w;    w += align256((size_t)2 * EE * 4);      // 6.4 MB
    int*   btot    = (int*)w;    w += align256((size_t)NB2 * 4);
    int*   bbase   = (int*)w;    w += align256((size_t)NB2 * 4);
    float* pcls    = (float*)w;  w += align256((size_t)NTB * 4);
    float* pdom    = (float*)w;  w += align256((size_t)2 * NTB * 4);
    ushort* pcnt   = (ushort*)w; w += align256((size_t)4 * HRNG * HSUB * HBIN * 2); // 12.8 MB

    const int TB = 256;
    k_cast_wt<INF><<<(INF * HH + TB - 1) / TB, TB, 0, stream>>>(W0, W0t);
    k_cast_wt<HH><<<(HH * HH + TB - 1) / TB, TB, 0, stream>>>(W1, W1t);
    k_cast_wtail<<<(16 * HH + TB - 1) / TB, TB, 0, stream>>>(Wfc, Wd, Wt1);
    k_cast_wtail2<<<(16 * HH + TB - 1) / TB, TB, 0, stream>>>(Wd, Wt2);

    // batched CSR prep for both graphs (LDS-histogram degrees, no global atomics)
    k_deghist<<<4 * HRNG * HSUB, TB, 0, stream>>>(src_s, dst_s, src_t, dst_t, pcnt);
    k_degsum<<<(4 * NN + TB - 1) / TB, TB, 0, stream>>>(pcnt, cnt);
    k_scan_blk<<<NB2, TB, 0, stream>>>(cnt, csr_off, btot);
    k_scan_tops<<<1, 512, 0, stream>>>(btot, bbase, csr_off);
    k_scan_fin<<<NB2, TB, 0, stream>>>(csr_off, bbase, csr_cur, cnt, ns, nd);
    k_fill_part<<<NFB * 8, TB, 0, stream>>>(src_s, dst_s, src_t, dst_t,
                                            csr_cur, csr_src);

    const int GB = (NN + 127) / 128;   // 391
    for (int g = 0; g < 2; ++g) {
        const float* feats = g ? features_t : features_s;
        const int*   offg  = csr_off + (size_t)g * NN;
        const float* nsg   = ns + (size_t)g * NN;
        const float* ndg   = nd + (size_t)g * NN;

        k_gemm<INF, true><<<GB, TB, 0, stream>>>(feats, W0t, nsg, y2);
        k_spmm5<<<SPMM_BLOCKS, TB, 0, stream>>>(y2, offg, csr_src, ndg, b0, h0);
        k_gemm<HH, false><<<GB, TB, 0, stream>>>(h0, W1t, nsg, y2);
        k_spmm5<<<SPMM_BLOCKS, TB, 0, stream>>>(y2, offg, csr_src, ndg, b1, h1);
        k_tail_mfma<<<NTB, TB, 0, stream>>>(h0, h1, Wt1, Wt2, bfc, bd, labels_s, g,
                                            pcls, pdom);
    }
    k_finalize<<<1, TB, 0, stream>>>(pcls, pdom, out);
}

// Round 11
// 474.094 us; speedup vs baseline: 2.8953x; 1.1973x over previous
//
#include <hip/hip_runtime.h>
#include <cstdint>
#include <cstddef>

#define NN 50000
#define NNP 50016          // y2 row stride per group (row NN = zero row)
#define EE 800000
#define INF 512
#define HH  256
#define CC  10
#define NB2 391            // ceil(2*NN/256) scan blocks
#define NTB 782            // ceil(NN/64)  tail blocks
#define SPMM_BLOCKS 1600   // 200 blocks per column group x 8 groups
#define NFB 104            // fill blocks per partition
#define PSZ 12500          // nodes per fill partition (2*NN/8)
#define HBIN 6250          // histogram bins per range task (25KB LDS)
#define HRNG 8             // ranges per array (8*6250 = NN)
#define HSUB 32            // sub-blocks per task
#define SCAP 1536
#define ZROW NN            // zero-row index within a y2 group slice

using bfrag = __attribute__((ext_vector_type(8))) __bf16;
using f32x4 = __attribute__((ext_vector_type(4))) float;

__device__ inline unsigned short f2bf(float x) {
    unsigned u = __builtin_bit_cast(unsigned, x);
    unsigned r = u + 0x7FFFu + ((u >> 16) & 1u);
    return (unsigned short)(r >> 16);
}
__device__ inline float bf2f(unsigned short h) {
    return __builtin_bit_cast(float, (unsigned)h << 16);
}

__device__ inline void gload_lds16(const void* gsrc, void* ldst) {
    __builtin_amdgcn_global_load_lds(
        (const __attribute__((address_space(1))) void*)gsrc,
        (__attribute__((address_space(3))) void*)ldst, 16, 0, 0);
}

// ---------------------------------------------------------------- weight casts
template<int K>
__global__ void k_cast_wt(const float* __restrict__ W, ushort* __restrict__ Wt) {
    int idx = blockIdx.x * blockDim.x + threadIdx.x;
    if (idx >= K * HH) return;
    int n = idx / K, k = idx % K;
    Wt[idx] = f2bf(W[(size_t)k * HH + n]);
}

__global__ void k_cast_wtail(const float* __restrict__ Wfc, const float* __restrict__ Wd,
                             ushort* __restrict__ Wt1) {
    int idx = blockIdx.x * blockDim.x + threadIdx.x;
    if (idx >= 16 * HH) return;
    int n = idx >> 8, k = idx & 255;
    float v = 0.f;
    if (n < 10)       v = Wfc[(size_t)k * 10 + n];
    else if (n < 12)  v = Wd[(size_t)(HH + k) * 2 + (n - 10)];
    Wt1[idx] = f2bf(v);
}

__global__ void k_cast_wtail2(const float* __restrict__ Wd, ushort* __restrict__ Wt2) {
    int idx = blockIdx.x * blockDim.x + threadIdx.x;
    if (idx >= 16 * HH) return;
    int n = idx >> 8, k = idx & 255;
    float v = (n < 2) ? Wd[(size_t)k * 2 + n] : 0.f;
    Wt2[idx] = f2bf(v);
}

// ---------------------------------------------------------------- LDS histogram degrees
__global__ __launch_bounds__(256) void k_deghist(
        const int* __restrict__ src_s, const int* __restrict__ dst_s,
        const int* __restrict__ src_t, const int* __restrict__ dst_t,
        ushort* __restrict__ pcnt) {
    __shared__ int hist[HBIN];
    const int task = blockIdx.x >> 5;    // 0..31
    const int sub  = blockIdx.x & 31;    // 0..31
    const int arr = task >> 3, range = task & 7;
    const int* p = (arr == 0) ? src_s : (arr == 1) ? dst_s : (arr == 2) ? src_t : dst_t;
    const int4* p4 = reinterpret_cast<const int4*>(p);
    const int lo = range * HBIN;
    for (int j = threadIdx.x; j < HBIN; j += 256) hist[j] = 0;
    __syncthreads();
    for (int i = sub * 256 + (int)threadIdx.x; i < EE / 4; i += HSUB * 256) {
        int4 v = p4[i];
        int a0 = v.x - lo, a1 = v.y - lo, a2 = v.z - lo, a3 = v.w - lo;
        if ((unsigned)a0 < (unsigned)HBIN) atomicAdd(&hist[a0], 1);
        if ((unsigned)a1 < (unsigned)HBIN) atomicAdd(&hist[a1], 1);
        if ((unsigned)a2 < (unsigned)HBIN) atomicAdd(&hist[a2], 1);
        if ((unsigned)a3 < (unsigned)HBIN) atomicAdd(&hist[a3], 1);
    }
    __syncthreads();
    ushort* out = pcnt + ((size_t)task * HSUB + sub) * HBIN;
    for (int j = threadIdx.x; j < HBIN; j += 256) out[j] = (ushort)hist[j];
}

__global__ void k_degsum(const ushort* __restrict__ pcnt, int* __restrict__ cnt) {
    int g = blockIdx.x * blockDim.x + threadIdx.x;
    if (g >= 4 * NN) return;
    int arr = g / NN;
    int node = g - arr * NN;
    int range = node / HBIN;
    int j = node - range * HBIN;
    const ushort* p = pcnt + ((size_t)(arr * HRNG + range) * HSUB) * HBIN + j;
    int s = 0;
    #pragma unroll
    for (int k = 0; k < HSUB; ++k) s += p[(size_t)k * HBIN];
    cnt[g] = s;
}

// ------------------------------------------------- 3-phase scan over in-degrees (2NN)
__global__ void k_scan_blk(const int* __restrict__ cnt, int* __restrict__ off,
                           int* __restrict__ btot) {
    __shared__ int wsum[4];
    int tid = threadIdx.x, lane = tid & 63, wid = tid >> 6;
    int i = blockIdx.x * 256 + tid;
    int v = 0;
    if (i < 2 * NN) v = (i < NN) ? cnt[NN + i] : cnt[2 * NN + i];
    int s = v;
    #pragma unroll
    for (int o = 1; o < 64; o <<= 1) {
        int t = __shfl_up(s, o, 64);
        if (lane >= o) s += t;
    }
    if (lane == 63) wsum[wid] = s;
    __syncthreads();
    if (tid == 0) {
        int a = 0;
        #pragma unroll
        for (int w2 = 0; w2 < 4; ++w2) { int t = wsum[w2]; wsum[w2] = a; a += t; }
        btot[blockIdx.x] = a;
    }
    __syncthreads();
    if (i < 2 * NN) off[i] = wsum[wid] + s - v;
}

__global__ void k_scan_tops(const int* __restrict__ btot, int* __restrict__ bbase,
                            int* __restrict__ off) {
    __shared__ int wsum[8];
    int tid = threadIdx.x, lane = tid & 63, wid = tid >> 6;
    int v = (tid < NB2) ? btot[tid] : 0;
    int s = v;
    #pragma unroll
    for (int o = 1; o < 64; o <<= 1) {
        int t = __shfl_up(s, o, 64);
        if (lane >= o) s += t;
    }
    if (lane == 63) wsum[wid] = s;
    __syncthreads();
    if (tid == 0) {
        int a = 0;
        #pragma unroll
        for (int w2 = 0; w2 < 8; ++w2) { int t = wsum[w2]; wsum[w2] = a; a += t; }
        off[2 * NN] = a;
    }
    __syncthreads();
    if (tid < NB2) bbase[tid] = wsum[wid] + s - v;
}

// fixup + norms + cur copy + zero-row init for y2
__global__ void k_scan_fin(int* __restrict__ off, const int* __restrict__ bbase,
                           int* __restrict__ cur, const int* __restrict__ cnt,
                           float* __restrict__ ns, float* __restrict__ nd,
                           ushort* __restrict__ y2) {
    if (blockIdx.x == 0 && threadIdx.x < 256) {
        int g = threadIdx.x >> 5, c = threadIdx.x & 31;
        y2[((size_t)g * NNP + ZROW) * 32 + c] = 0;
    }
    int i = blockIdx.x * blockDim.x + threadIdx.x;
    if (i >= 2 * NN) return;
    int o = off[i] + bbase[i >> 8];
    off[i] = o;
    cur[i] = o;
    int co = (i < NN) ? cnt[i] : cnt[NN + i];          // out-degree
    int ci = (i < NN) ? cnt[NN + i] : cnt[2 * NN + i]; // in-degree
    ns[i] = 1.0f / sqrtf(fmaxf((float)co, 1.0f));
    nd[i] = 1.0f / sqrtf(fmaxf((float)ci, 1.0f));
}

// ------------------------------------------------- partitioned CSR fill
__global__ __launch_bounds__(256) void k_fill_part(
        const int* __restrict__ src_s, const int* __restrict__ dst_s,
        const int* __restrict__ src_t, const int* __restrict__ dst_t,
        int* __restrict__ cur, int* __restrict__ csr_src) {
    const int p = blockIdx.x & 7;
    const int blk = blockIdx.x >> 3;      // 0..NFB-1
    const unsigned lo = p * PSZ;
    for (int e = blk * 256 + (int)threadIdx.x; e < 2 * EE; e += NFB * 256) {
        int node;
        if (e < EE) node = dst_s[e];
        else        node = NN + dst_t[e - EE];
        if ((unsigned)(node - lo) < (unsigned)PSZ) {
            int sv = (e < EE) ? src_s[e] : src_t[e - EE];
            int pos = atomicAdd(&cur[node], 1);
            csr_src[pos] = sv;
        }
    }
}

// ---------------------------------------------------------------- MFMA GEMM
// BM=128, BN=256. y2 output in grouped layout [8][NNP][32].
// B tiles (and A tiles when bf16) staged via global_load_lds with
// pre-swizzled global source (linear LDS dest == lane*16).
template<int K, bool F32A>
__global__ __launch_bounds__(256, 2) void k_gemm(
        const void* __restrict__ Ap, const ushort* __restrict__ Bt,
        const float* __restrict__ ns, ushort* __restrict__ y2) {
    __shared__ ushort As[128 * 64];
    __shared__ ushort Bs[256 * 64];
    const int m0 = blockIdx.x * 128;
    const int t = threadIdx.x;
    const int wid = t >> 6, lane = t & 63;
    const int wr = (wid & 1) * 64;
    const int wc = (wid >> 1) * 128;
    const int l15 = lane & 15, lg = lane >> 4;

    f32x4 acc[4][8];
    #pragma unroll
    for (int m = 0; m < 4; ++m)
        #pragma unroll
        for (int n = 0; n < 8; ++n)
            acc[m][n] = {0.f, 0.f, 0.f, 0.f};

    const int srow = t >> 3;
    const int schunk = t & 7;

    for (int k0 = 0; k0 < K; k0 += 64) {
        if constexpr (F32A) {
            #pragma unroll
            for (int i = 0; i < 4; ++i) {        // A tile 128x64, fp32->bf16 convert
                int row = srow + i * 32;
                int sw = ((schunk ^ (row & 7)) * 8);
                int m = m0 + row; if (m >= NN) m = NN - 1;
                const float* ap = (const float*)Ap + (size_t)m * K + k0 + schunk * 8;
                float4 f0 = *reinterpret_cast<const float4*>(ap);
                float4 f1 = *reinterpret_cast<const float4*>(ap + 4);
                uint4 va;
                va.x = (unsigned)f2bf(f0.x) | ((unsigned)f2bf(f0.y) << 16);
                va.y = (unsigned)f2bf(f0.z) | ((unsigned)f2bf(f0.w) << 16);
                va.z = (unsigned)f2bf(f1.x) | ((unsigned)f2bf(f1.y) << 16);
                va.w = (unsigned)f2bf(f1.z) | ((unsigned)f2bf(f1.w) << 16);
                *reinterpret_cast<uint4*>(&As[row * 64 + sw]) = va;
            }
        } else {
            #pragma unroll
            for (int i = 0; i < 4; ++i) {        // A tile 128x64, direct to LDS
                int row = srow + i * 32;
                int sw = ((schunk ^ (row & 7)) * 8);
                int m = m0 + row; if (m >= NN) m = NN - 1;
                const ushort* gsrc = (const ushort*)Ap + (size_t)m * K + k0 + sw;
                gload_lds16(gsrc, &As[(size_t)(wid * 8 + i * 32) * 64]);
            }
        }
        #pragma unroll
        for (int i = 0; i < 8; ++i) {            // B tile 256x64, direct to LDS
            int row = srow + i * 32;
            int sw = ((schunk ^ (row & 7)) * 8);
            const ushort* gsrc = &Bt[(size_t)row * K + k0 + sw];
            gload_lds16(gsrc, &Bs[(size_t)(wid * 8 + i * 32) * 64]);
        }
        __syncthreads();
        #pragma unroll
        for (int kk = 0; kk < 64; kk += 32) {
            const int kc = kk >> 3;
            bfrag af[4];
            #pragma unroll
            for (int m = 0; m < 4; ++m) {
                int row = wr + m * 16 + l15;
                af[m] = *reinterpret_cast<const bfrag*>(&As[row * 64 + (((lg + kc) ^ (row & 7)) * 8)]);
            }
            #pragma unroll
            for (int n = 0; n < 8; ++n) {
                int row = wc + n * 16 + l15;
                bfrag bg = *reinterpret_cast<const bfrag*>(&Bs[row * 64 + (((lg + kc) ^ (row & 7)) * 8)]);
                #pragma unroll
                for (int m = 0; m < 4; ++m)
                    acc[m][n] = __builtin_amdgcn_mfma_f32_16x16x32_bf16(af[m], bg, acc[m][n], 0, 0, 0);
            }
        }
        __syncthreads();
    }
    #pragma unroll
    for (int m = 0; m < 4; ++m) {
        #pragma unroll
        for (int r = 0; r < 4; ++r) {
            int row = m0 + wr + m * 16 + lg * 4 + r;
            if (row >= NN) continue;
            float nsv = ns[row];
            #pragma unroll
            for (int n = 0; n < 8; ++n) {
                int col = wc + n * 16 + l15;
                int grp = col >> 5, colw = col & 31;
                y2[((size_t)grp * NNP + row) * 32 + colw] = f2bf(acc[m][n][r] * nsv);
            }
        }
    }
}

// ------------------------------------------------- SpMM: branchless chains
// grp = blockIdx&7 -> contiguous L2-resident slice [NNP][32]. Invalid edges
// redirect to zero row (single cndmask); uniform LDS-vs-global path choice.
__device__ inline void add8(float* a, uint4 v) {
    a[0] += __builtin_bit_cast(float, v.x << 16);
    a[1] += __builtin_bit_cast(float, v.x & 0xffff0000u);
    a[2] += __builtin_bit_cast(float, v.y << 16);
    a[3] += __builtin_bit_cast(float, v.y & 0xffff0000u);
    a[4] += __builtin_bit_cast(float, v.z << 16);
    a[5] += __builtin_bit_cast(float, v.z & 0xffff0000u);
    a[6] += __builtin_bit_cast(float, v.w << 16);
    a[7] += __builtin_bit_cast(float, v.w & 0xffff0000u);
}

__global__ __launch_bounds__(256) void k_spmm6(
        const ushort* __restrict__ y2, const int* __restrict__ off,
        const int* __restrict__ csr_src, const float* __restrict__ nd_arr,
        const float* __restrict__ bias, ushort* __restrict__ h_out) {
    __shared__ int sidx[4][SCAP];
    const int grp = blockIdx.x & 7;
    const int blk = blockIdx.x >> 3;          // 0..199
    const int tid = threadIdx.x;
    const int lane = tid & 63, wid = tid >> 6;
    const int slot = lane >> 2;               // 0..15
    const int sub = lane & 3;                 // 16B sub-chunk of the 32-col slice
    const ushort* ybase = y2 + (size_t)grp * NNP * 32 + sub * 8;

    const int nb = (blk * 4 + wid) * 64;
    int s_wave0 = 0, cnt = 0;
    if (nb < NN) {
        int nend = nb + 64 < NN ? nb + 64 : NN;
        s_wave0 = off[nb];
        cnt = off[nend] - s_wave0;
    }
    int stage = cnt < SCAP ? cnt : SCAP;
    for (int j = lane; j < stage; j += 64)
        sidx[wid][j] = csr_src[s_wave0 + j];
    __syncthreads();

    float bia[8];
    #pragma unroll
    for (int j = 0; j < 8; ++j) bia[j] = bias[grp * 32 + sub * 8 + j];

    int e0[4], e1[4];
    float a[4][8];
    #pragma unroll
    for (int c = 0; c < 4; ++c) {
        int n = nb + c * 16 + slot;
        bool v = n < NN;
        e0[c] = v ? off[n] - s_wave0 : 0;
        e1[c] = v ? off[n + 1] - s_wave0 : 0;
        #pragma unroll
        for (int j = 0; j < 8; ++j) a[c][j] = 0.f;
    }
    int tmax = max(max(e1[0] - e0[0], e1[1] - e0[1]), max(e1[2] - e0[2], e1[3] - e0[3]));

    if (cnt <= SCAP) {
        for (int t = 0; t < tmax; ++t) {
            uint4 v[4];
            #pragma unroll
            for (int c = 0; c < 4; ++c) {
                int ec = e0[c] + t;
                bool val = ec < e1[c];
                int ecc = val ? ec : 0;
                int id = sidx[wid][ecc];
                id = val ? id : ZROW;
                v[c] = *reinterpret_cast<const uint4*>(&ybase[(size_t)id * 32]);
            }
            #pragma unroll
            for (int c = 0; c < 4; ++c) add8(a[c], v[c]);
        }
    } else {
        for (int t = 0; t < tmax; ++t) {
            uint4 v[4];
            #pragma unroll
            for (int c = 0; c < 4; ++c) {
                int ec = e0[c] + t;
                bool val = ec < e1[c];
                int ecc = val ? ec : 0;
                int id = csr_src[s_wave0 + ecc];
                id = val ? id : ZROW;
                v[c] = *reinterpret_cast<const uint4*>(&ybase[(size_t)id * 32]);
            }
            #pragma unroll
            for (int c = 0; c < 4; ++c) add8(a[c], v[c]);
        }
    }

    #pragma unroll
    for (int c = 0; c < 4; ++c) {
        int n = nb + c * 16 + slot;
        if (n >= NN) continue;
        float nd = nd_arr[n];
        ushort r[8];
        #pragma unroll
        for (int j = 0; j < 8; ++j) r[j] = f2bf(fmaxf(a[c][j] * nd + bia[j], 0.f));
        uint4 pk;
        pk.x = (unsigned)r[0] | ((unsigned)r[1] << 16);
        pk.y = (unsigned)r[2] | ((unsigned)r[3] << 16);
        pk.z = (unsigned)r[4] | ((unsigned)r[5] << 16);
        pk.w = (unsigned)r[6] | ((unsigned)r[7] << 16);
        *reinterpret_cast<uint4*>(&h_out[(size_t)n * 256 + grp * 32 + sub * 8]) = pk;
    }
}

// ------------------------------------------------- MFMA tail: fc + dlog + losses
__global__ __launch_bounds__(256) void k_tail_mfma(
        const ushort* __restrict__ h0, const ushort* __restrict__ h1,
        const ushort* __restrict__ Wt1, const ushort* __restrict__ Wt2,
        const float* __restrict__ bfc, const float* __restrict__ bd,
        const int* __restrict__ labels, int g,
        float* __restrict__ pcls, float* __restrict__ pdom) {
    __shared__ float sT1[4][16][17];
    __shared__ float sT2[4][16][17];
    __shared__ float sc[4], sd[4];
    const int tid = threadIdx.x;
    const int wid = tid >> 6, lane = tid & 63;
    const int l15 = lane & 15, lg = lane >> 4;
    const int base = blockIdx.x * 64 + wid * 16;

    int arow = base + l15; if (arow >= NN) arow = NN - 1;
    const ushort* a1 = h1 + (size_t)arow * 256 + lg * 8;
    const ushort* a0 = h0 + (size_t)arow * 256 + lg * 8;
    const ushort* b1 = Wt1 + (size_t)l15 * 256 + lg * 8;
    const ushort* b2 = Wt2 + (size_t)l15 * 256 + lg * 8;
    f32x4 acc1 = {0.f, 0.f, 0.f, 0.f};
    f32x4 acc2 = {0.f, 0.f, 0.f, 0.f};
    #pragma unroll
    for (int kk = 0; kk < 8; ++kk) {
        bfrag af1 = *reinterpret_cast<const bfrag*>(a1 + kk * 32);
        bfrag bg1 = *reinterpret_cast<const bfrag*>(b1 + kk * 32);
        acc1 = __builtin_amdgcn_mfma_f32_16x16x32_bf16(af1, bg1, acc1, 0, 0, 0);
        bfrag af0 = *reinterpret_cast<const bfrag*>(a0 + kk * 32);
        bfrag bg2 = *reinterpret_cast<const bfrag*>(b2 + kk * 32);
        acc2 = __builtin_amdgcn_mfma_f32_16x16x32_bf16(af0, bg2, acc2, 0, 0, 0);
    }
    #pragma unroll
    for (int j = 0; j < 4; ++j) {
        sT1[wid][lg * 4 + j][l15] = acc1[j];
        sT2[wid][lg * 4 + j][l15] = acc2[j];
    }
    __syncthreads();

    float cls = 0.f, dom = 0.f;
    int n = base + lane;
    if (lane < 16 && n < NN) {
        float lgt[10];
        #pragma unroll
        for (int c = 0; c < 10; ++c) lgt[c] = sT1[wid][lane][c] + bfc[c];
        float dl0 = bd[0] + sT2[wid][lane][0] + sT1[wid][lane][10];
        float dl1 = bd[1] + sT2[wid][lane][1] + sT1[wid][lane][11];
        if (g == 0) {
            float m = lgt[0];
            #pragma unroll
            for (int c = 1; c < 10; ++c) m = fmaxf(m, lgt[c]);
            float s = 0.f;
            #pragma unroll
            for (int c = 0; c < 10; ++c) s += expf(lgt[c] - m);
            int lab = labels[n];
            float tgt = lgt[0];
            #pragma unroll
            for (int c = 1; c < 10; ++c) tgt = (c == lab) ? lgt[c] : tgt;
            cls = -(tgt - (m + logf(s)));
        }
        float m2 = fmaxf(dl0, dl1);
        float lse2 = m2 + logf(expf(dl0 - m2) + expf(dl1 - m2));
        dom = -((g ? dl1 : dl0) - lse2);
    }
    #pragma unroll
    for (int o = 1; o < 16; o <<= 1) {
        cls += __shfl_xor(cls, o, 64);
        dom += __shfl_xor(dom, o, 64);
    }
    if (lane == 0) { sc[wid] = cls; sd[wid] = dom; }
    __syncthreads();
    if (tid == 0) {
        float c = sc[0] + sc[1] + sc[2] + sc[3];
        float d = sd[0] + sd[1] + sd[2] + sd[3];
        if (g == 0) pcls[blockIdx.x] = c;
        pdom[g * NTB + blockIdx.x] = d;
    }
}

__global__ void k_finalize(const float* __restrict__ pcls, const float* __restrict__ pdom,
                           float* __restrict__ out) {
    __shared__ float sc[4], sd[4];
    int tid = threadIdx.x, lane = tid & 63, wid = tid >> 6;
    float c = 0.f, d = 0.f;
    for (int i = tid; i < NTB; i += 256) c += pcls[i];
    for (int i = tid; i < 2 * NTB; i += 256) d += pdom[i];
    #pragma unroll
    for (int o = 32; o; o >>= 1) {
        c += __shfl_xor(c, o, 64);
        d += __shfl_xor(d, o, 64);
    }
    if (lane == 0) { sc[wid] = c; sd[wid] = d; }
    __syncthreads();
    if (tid == 0) {
        float ct = sc[0] + sc[1] + sc[2] + sc[3];
        float dt = sd[0] + sd[1] + sd[2] + sd[3];
        out[0] = ct / (float)NN + 0.01f * (dt / (float)(2 * NN));
    }
}

// ---------------------------------------------------------------- launch
extern "C" void kernel_launch(void* const* d_in, const int* in_sizes, int n_in,
                              void* d_out, int out_size, void* d_ws, size_t ws_size,
                              hipStream_t stream) {
    const float* features_s = (const float*)d_in[0];
    const int*   labels_s   = (const int*)d_in[1];
    const float* features_t = (const float*)d_in[2];
    const int*   src_s      = (const int*)d_in[3];
    const int*   dst_s      = (const int*)d_in[4];
    const int*   src_t      = (const int*)d_in[5];
    const int*   dst_t      = (const int*)d_in[6];
    const float* W0         = (const float*)d_in[7];
    const float* b0         = (const float*)d_in[8];
    const float* W1         = (const float*)d_in[9];
    const float* b1         = (const float*)d_in[10];
    const float* Wfc        = (const float*)d_in[11];
    const float* bfc        = (const float*)d_in[12];
    const float* Wd         = (const float*)d_in[13];
    const float* bd         = (const float*)d_in[14];
    float* out = (float*)d_out;

    auto align256 = [](size_t x) { return (x + 255) & ~(size_t)255; };
    char* w = (char*)d_ws;
    ushort* h0     = (ushort*)w; w += align256((size_t)NN * HH * 2);     // 25.6 MB
    ushort* h1     = (ushort*)w; w += align256((size_t)NN * HH * 2);     // 25.6 MB
    ushort* y2     = (ushort*)w; w += align256((size_t)NNP * HH * 2);    // 25.6 MB grouped
    ushort* W0t    = (ushort*)w; w += align256((size_t)INF * HH * 2);
    ushort* W1t    = (ushort*)w; w += align256((size_t)HH * HH * 2);
    ushort* Wt1    = (ushort*)w; w += align256((size_t)16 * HH * 2);
    ushort* Wt2    = (ushort*)w; w += align256((size_t)16 * HH * 2);
    float* ns      = (float*)w;  w += align256((size_t)2 * NN * 4);
    float* nd      = (float*)w;  w += align256((size_t)2 * NN * 4);
    int*   cnt     = (int*)w;    w += align256((size_t)4 * NN * 4);
    int*   csr_off = (int*)w;    w += align256((size_t)(2 * NN + 1) * 4);
    int*   csr_cur = (int*)w;    w += align256((size_t)2 * NN * 4);
    int*   csr_src = (int*)w;    w += align256((size_t)2 * EE * 4);      // 6.4 MB
    int*   btot    = (int*)w;    w += align256((size_t)NB2 * 4);
    int*   bbase   = (int*)w;    w += align256((size_t)NB2 * 4);
    float* pcls    = (float*)w;  w += align256((size_t)NTB * 4);
    float* pdom    = (float*)w;  w += align256((size_t)2 * NTB * 4);
    ushort* pcnt   = (ushort*)w; w += align256((size_t)4 * HRNG * HSUB * HBIN * 2); // 12.8 MB

    const int TB = 256;
    k_cast_wt<INF><<<(INF * HH + TB - 1) / TB, TB, 0, stream>>>(W0, W0t);
    k_cast_wt<HH><<<(HH * HH + TB - 1) / TB, TB, 0, stream>>>(W1, W1t);
    k_cast_wtail<<<(16 * HH + TB - 1) / TB, TB, 0, stream>>>(Wfc, Wd, Wt1);
    k_cast_wtail2<<<(16 * HH + TB - 1) / TB, TB, 0, stream>>>(Wd, Wt2);

    // batched CSR prep for both graphs (LDS-histogram degrees, no global atomics)
    k_deghist<<<4 * HRNG * HSUB, TB, 0, stream>>>(src_s, dst_s, src_t, dst_t, pcnt);
    k_degsum<<<(4 * NN + TB - 1) / TB, TB, 0, stream>>>(pcnt, cnt);
    k_scan_blk<<<NB2, TB, 0, stream>>>(cnt, csr_off, btot);
    k_scan_tops<<<1, 512, 0, stream>>>(btot, bbase, csr_off);
    k_scan_fin<<<NB2, TB, 0, stream>>>(csr_off, bbase, csr_cur, cnt, ns, nd, y2);
    k_fill_part<<<NFB * 8, TB, 0, stream>>>(src_s, dst_s, src_t, dst_t,
                                            csr_cur, csr_src);

    const int GB = (NN + 127) / 128;   // 391
    for (int g = 0; g < 2; ++g) {
        const float* feats = g ? features_t : features_s;
        const int*   offg  = csr_off + (size_t)g * NN;
        const float* nsg   = ns + (size_t)g * NN;
        const float* ndg   = nd + (size_t)g * NN;

        k_gemm<INF, true><<<GB, TB, 0, stream>>>(feats, W0t, nsg, y2);
        k_spmm6<<<SPMM_BLOCKS, TB, 0, stream>>>(y2, offg, csr_src, ndg, b0, h0);
        k_gemm<HH, false><<<GB, TB, 0, stream>>>(h0, W1t, nsg, y2);
        k_spmm6<<<SPMM_BLOCKS, TB, 0, stream>>>(y2, offg, csr_src, ndg, b1, h1);
        k_tail_mfma<<<NTB, TB, 0, stream>>>(h0, h1, Wt1, Wt2, bfc, bd, labels_s, g,
                                            pcls, pdom);
    }
    k_finalize<<<1, TB, 0, stream>>>(pcls, pdom, out);
}

// Round 13
// 443.473 us; speedup vs baseline: 3.0952x; 1.0690x over previous
//
#include <hip/hip_runtime.h>
#include <cstdint>
#include <cstddef>

#define NN 50000
#define NNP 50016          // y2 row stride per group (row NN = zero row)
#define EE 800000
#define INF 512
#define HH  256
#define CC  10
#define NB2 391            // ceil(2*NN/256) scan blocks
#define NTB 782            // ceil(NN/64)  tail blocks
#define SPMM_BLOCKS 1600   // 200 blocks per column group x 8 groups
#define HBIN 6250          // histogram bins per range task (25KB LDS)
#define HRNG 8             // ranges per array (8*6250 = NN)
#define HSUB 32            // sub-blocks per task
#define SCAP 1536
#define ZROW NN            // zero-row index within a y2 group slice

using bfrag = __attribute__((ext_vector_type(8))) __bf16;
using f32x4 = __attribute__((ext_vector_type(4))) float;

__device__ inline unsigned short f2bf(float x) {
    unsigned u = __builtin_bit_cast(unsigned, x);
    unsigned r = u + 0x7FFFu + ((u >> 16) & 1u);
    return (unsigned short)(r >> 16);
}
__device__ inline float bf2f(unsigned short h) {
    return __builtin_bit_cast(float, (unsigned)h << 16);
}

__device__ inline void gload_lds16(const void* gsrc, void* ldst) {
    __builtin_amdgcn_global_load_lds(
        (const __attribute__((address_space(1))) void*)gsrc,
        (__attribute__((address_space(3))) void*)ldst, 16, 0, 0);
}

// ---------------------------------------------------------------- weight casts
template<int K>
__global__ void k_cast_wt(const float* __restrict__ W, ushort* __restrict__ Wt) {
    int idx = blockIdx.x * blockDim.x + threadIdx.x;
    if (idx >= K * HH) return;
    int n = idx / K, k = idx % K;
    Wt[idx] = f2bf(W[(size_t)k * HH + n]);
}

__global__ void k_cast_wtail(const float* __restrict__ Wfc, const float* __restrict__ Wd,
                             ushort* __restrict__ Wt1) {
    int idx = blockIdx.x * blockDim.x + threadIdx.x;
    if (idx >= 16 * HH) return;
    int n = idx >> 8, k = idx & 255;
    float v = 0.f;
    if (n < 10)       v = Wfc[(size_t)k * 10 + n];
    else if (n < 12)  v = Wd[(size_t)(HH + k) * 2 + (n - 10)];
    Wt1[idx] = f2bf(v);
}

__global__ void k_cast_wtail2(const float* __restrict__ Wd, ushort* __restrict__ Wt2) {
    int idx = blockIdx.x * blockDim.x + threadIdx.x;
    if (idx >= 16 * HH) return;
    int n = idx >> 8, k = idx & 255;
    float v = (n < 2) ? Wd[(size_t)k * 2 + n] : 0.f;
    Wt2[idx] = f2bf(v);
}

// ---------------------------------------------------------------- LDS histogram degrees
__global__ __launch_bounds__(256) void k_deghist(
        const int* __restrict__ src_s, const int* __restrict__ dst_s,
        const int* __restrict__ src_t, const int* __restrict__ dst_t,
        ushort* __restrict__ pcnt) {
    __shared__ int hist[HBIN];
    const int task = blockIdx.x >> 5;    // 0..31
    const int sub  = blockIdx.x & 31;    // 0..31
    const int arr = task >> 3, range = task & 7;
    const int* p = (arr == 0) ? src_s : (arr == 1) ? dst_s : (arr == 2) ? src_t : dst_t;
    const int4* p4 = reinterpret_cast<const int4*>(p);
    const int lo = range * HBIN;
    for (int j = threadIdx.x; j < HBIN; j += 256) hist[j] = 0;
    __syncthreads();
    for (int i = sub * 256 + (int)threadIdx.x; i < EE / 4; i += HSUB * 256) {
        int4 v = p4[i];
        int a0 = v.x - lo, a1 = v.y - lo, a2 = v.z - lo, a3 = v.w - lo;
        if ((unsigned)a0 < (unsigned)HBIN) atomicAdd(&hist[a0], 1);
        if ((unsigned)a1 < (unsigned)HBIN) atomicAdd(&hist[a1], 1);
        if ((unsigned)a2 < (unsigned)HBIN) atomicAdd(&hist[a2], 1);
        if ((unsigned)a3 < (unsigned)HBIN) atomicAdd(&hist[a3], 1);
    }
    __syncthreads();
    ushort* out = pcnt + ((size_t)task * HSUB + sub) * HBIN;
    for (int j = threadIdx.x; j < HBIN; j += 256) out[j] = (ushort)hist[j];
}

__global__ void k_degsum(const ushort* __restrict__ pcnt, int* __restrict__ cnt) {
    int g = blockIdx.x * blockDim.x + threadIdx.x;
    if (g >= 4 * NN) return;
    int arr = g / NN;
    int node = g - arr * NN;
    int range = node / HBIN;
    int j = node - range * HBIN;
    const ushort* p = pcnt + ((size_t)(arr * HRNG + range) * HSUB) * HBIN + j;
    int s = 0;
    #pragma unroll
    for (int k = 0; k < HSUB; ++k) s += p[(size_t)k * HBIN];
    cnt[g] = s;
}

// ------------------------------------------------- 3-phase scan over in-degrees (2NN)
__global__ void k_scan_blk(const int* __restrict__ cnt, int* __restrict__ off,
                           int* __restrict__ btot) {
    __shared__ int wsum[4];
    int tid = threadIdx.x, lane = tid & 63, wid = tid >> 6;
    int i = blockIdx.x * 256 + tid;
    int v = 0;
    if (i < 2 * NN) v = (i < NN) ? cnt[NN + i] : cnt[2 * NN + i];
    int s = v;
    #pragma unroll
    for (int o = 1; o < 64; o <<= 1) {
        int t = __shfl_up(s, o, 64);
        if (lane >= o) s += t;
    }
    if (lane == 63) wsum[wid] = s;
    __syncthreads();
    if (tid == 0) {
        int a = 0;
        #pragma unroll
        for (int w2 = 0; w2 < 4; ++w2) { int t = wsum[w2]; wsum[w2] = a; a += t; }
        btot[blockIdx.x] = a;
    }
    __syncthreads();
    if (i < 2 * NN) off[i] = wsum[wid] + s - v;
}

__global__ void k_scan_tops(const int* __restrict__ btot, int* __restrict__ bbase,
                            int* __restrict__ off) {
    __shared__ int wsum[8];
    int tid = threadIdx.x, lane = tid & 63, wid = tid >> 6;
    int v = (tid < NB2) ? btot[tid] : 0;
    int s = v;
    #pragma unroll
    for (int o = 1; o < 64; o <<= 1) {
        int t = __shfl_up(s, o, 64);
        if (lane >= o) s += t;
    }
    if (lane == 63) wsum[wid] = s;
    __syncthreads();
    if (tid == 0) {
        int a = 0;
        #pragma unroll
        for (int w2 = 0; w2 < 8; ++w2) { int t = wsum[w2]; wsum[w2] = a; a += t; }
        off[2 * NN] = a;
    }
    __syncthreads();
    if (tid < NB2) bbase[tid] = wsum[wid] + s - v;
}

// fixup + norms + zero-row init for y2
__global__ void k_scan_fin(int* __restrict__ off, const int* __restrict__ bbase,
                           const int* __restrict__ cnt,
                           float* __restrict__ ns, float* __restrict__ nd,
                           ushort* __restrict__ y2) {
    if (blockIdx.x == 0 && threadIdx.x < 256) {
        int g = threadIdx.x >> 5, c = threadIdx.x & 31;
        y2[((size_t)g * NNP + ZROW) * 32 + c] = 0;
    }
    int i = blockIdx.x * blockDim.x + threadIdx.x;
    if (i >= 2 * NN) return;
    int o = off[i] + bbase[i >> 8];
    off[i] = o;
    int co = (i < NN) ? cnt[i] : cnt[NN + i];          // out-degree
    int ci = (i < NN) ? cnt[NN + i] : cnt[2 * NN + i]; // in-degree
    ns[i] = 1.0f / sqrtf(fmaxf((float)co, 1.0f));
    nd[i] = 1.0f / sqrtf(fmaxf((float)ci, 1.0f));
}

// ------------------------------------------------- per-sub start positions
// base2[(g*HRNG+range)*HSUB+s][bin] = off[node] + sum_{s'<s} pcnt[dst-task][s'][bin]
__global__ void k_degpos(const ushort* __restrict__ pcnt, const int* __restrict__ off,
                         int* __restrict__ base2) {
    int i = blockIdx.x * blockDim.x + threadIdx.x;
    if (i >= 2 * NN) return;
    int g = (i < NN) ? 0 : 1;
    int node = i - g * NN;
    int range = node / HBIN;
    int bin = node - range * HBIN;
    int arr = g ? 3 : 1;                 // dst_s / dst_t tasks
    const ushort* p = pcnt + ((size_t)(arr * HRNG + range) * HSUB) * HBIN + bin;
    int* b = base2 + ((size_t)(g * HRNG + range) * HSUB) * HBIN + bin;
    int run = off[i];
    #pragma unroll
    for (int s = 0; s < HSUB; ++s) {
        b[(size_t)s * HBIN] = run;
        run += p[(size_t)s * HBIN];
    }
}

// ------------------------------------------------- CSR fill, LDS-atomic only
// block = (sub, combo); combo = g*8+range; blockIdx&7 = range (XCD-pinned csr window).
// CRITICAL: edge iteration must be the SAME strided partition as k_deghist,
// so each sub places exactly the edges it was counted for.
__global__ __launch_bounds__(256) void k_fill3(
        const int* __restrict__ src_s, const int* __restrict__ dst_s,
        const int* __restrict__ src_t, const int* __restrict__ dst_t,
        const int* __restrict__ base2, int* __restrict__ csr_src) {
    __shared__ int cur[HBIN];
    const int combo = blockIdx.x & 15;   // g*8 + range
    const int sub = blockIdx.x >> 4;     // 0..31
    const int g = combo >> 3, range = combo & 7;
    const int4* d4 = reinterpret_cast<const int4*>(g ? dst_t : dst_s);
    const int4* s4 = reinterpret_cast<const int4*>(g ? src_t : src_s);
    const int lo = range * HBIN;
    const int* b = base2 + (size_t)combo * HSUB * HBIN + (size_t)sub * HBIN;
    for (int j = threadIdx.x; j < HBIN; j += 256) cur[j] = b[j];
    __syncthreads();
    for (int i = sub * 256 + (int)threadIdx.x; i < EE / 4; i += HSUB * 256) {
        int4 d = d4[i];
        int b0 = d.x - lo, b1 = d.y - lo, b2 = d.z - lo, b3 = d.w - lo;
        bool o0 = (unsigned)b0 < (unsigned)HBIN;
        bool o1 = (unsigned)b1 < (unsigned)HBIN;
        bool o2 = (unsigned)b2 < (unsigned)HBIN;
        bool o3 = (unsigned)b3 < (unsigned)HBIN;
        if (o0 | o1 | o2 | o3) {
            int4 s = s4[i];
            if (o0) csr_src[atomicAdd(&cur[b0], 1)] = s.x;
            if (o1) csr_src[atomicAdd(&cur[b1], 1)] = s.y;
            if (o2) csr_src[atomicAdd(&cur[b2], 1)] = s.z;
            if (o3) csr_src[atomicAdd(&cur[b3], 1)] = s.w;
        }
    }
}

// ---------------------------------------------------------------- MFMA GEMM
// BM=128, BN=256. y2 output in grouped layout [8][NNP][32].
template<int K, bool F32A>
__global__ __launch_bounds__(256, 2) void k_gemm(
        const void* __restrict__ Ap, const ushort* __restrict__ Bt,
        const float* __restrict__ ns, ushort* __restrict__ y2) {
    __shared__ ushort As[128 * 64];
    __shared__ ushort Bs[256 * 64];
    const int m0 = blockIdx.x * 128;
    const int t = threadIdx.x;
    const int wid = t >> 6, lane = t & 63;
    const int wr = (wid & 1) * 64;
    const int wc = (wid >> 1) * 128;
    const int l15 = lane & 15, lg = lane >> 4;

    f32x4 acc[4][8];
    #pragma unroll
    for (int m = 0; m < 4; ++m)
        #pragma unroll
        for (int n = 0; n < 8; ++n)
            acc[m][n] = {0.f, 0.f, 0.f, 0.f};

    const int srow = t >> 3;
    const int schunk = t & 7;

    for (int k0 = 0; k0 < K; k0 += 64) {
        if constexpr (F32A) {
            #pragma unroll
            for (int i = 0; i < 4; ++i) {        // A tile 128x64, fp32->bf16 convert
                int row = srow + i * 32;
                int sw = ((schunk ^ (row & 7)) * 8);
                int m = m0 + row; if (m >= NN) m = NN - 1;
                const float* ap = (const float*)Ap + (size_t)m * K + k0 + schunk * 8;
                float4 f0 = *reinterpret_cast<const float4*>(ap);
                float4 f1 = *reinterpret_cast<const float4*>(ap + 4);
                uint4 va;
                va.x = (unsigned)f2bf(f0.x) | ((unsigned)f2bf(f0.y) << 16);
                va.y = (unsigned)f2bf(f0.z) | ((unsigned)f2bf(f0.w) << 16);
                va.z = (unsigned)f2bf(f1.x) | ((unsigned)f2bf(f1.y) << 16);
                va.w = (unsigned)f2bf(f1.z) | ((unsigned)f2bf(f1.w) << 16);
                *reinterpret_cast<uint4*>(&As[row * 64 + sw]) = va;
            }
        } else {
            #pragma unroll
            for (int i = 0; i < 4; ++i) {        // A tile 128x64, direct to LDS
                int row = srow + i * 32;
                int sw = ((schunk ^ (row & 7)) * 8);
                int m = m0 + row; if (m >= NN) m = NN - 1;
                const ushort* gsrc = (const ushort*)Ap + (size_t)m * K + k0 + sw;
                gload_lds16(gsrc, &As[(size_t)(wid * 8 + i * 32) * 64]);
            }
        }
        #pragma unroll
        for (int i = 0; i < 8; ++i) {            // B tile 256x64, direct to LDS
            int row = srow + i * 32;
            int sw = ((schunk ^ (row & 7)) * 8);
            const ushort* gsrc = &Bt[(size_t)row * K + k0 + sw];
            gload_lds16(gsrc, &Bs[(size_t)(wid * 8 + i * 32) * 64]);
        }
        __syncthreads();
        #pragma unroll
        for (int kk = 0; kk < 64; kk += 32) {
            const int kc = kk >> 3;
            bfrag af[4];
            #pragma unroll
            for (int m = 0; m < 4; ++m) {
                int row = wr + m * 16 + l15;
                af[m] = *reinterpret_cast<const bfrag*>(&As[row * 64 + (((lg + kc) ^ (row & 7)) * 8)]);
            }
            #pragma unroll
            for (int n = 0; n < 8; ++n) {
                int row = wc + n * 16 + l15;
                bfrag bg = *reinterpret_cast<const bfrag*>(&Bs[row * 64 + (((lg + kc) ^ (row & 7)) * 8)]);
                #pragma unroll
                for (int m = 0; m < 4; ++m)
                    acc[m][n] = __builtin_amdgcn_mfma_f32_16x16x32_bf16(af[m], bg, acc[m][n], 0, 0, 0);
            }
        }
        __syncthreads();
    }
    #pragma unroll
    for (int m = 0; m < 4; ++m) {
        #pragma unroll
        for (int r = 0; r < 4; ++r) {
            int row = m0 + wr + m * 16 + lg * 4 + r;
            if (row >= NN) continue;
            float nsv = ns[row];
            #pragma unroll
            for (int n = 0; n < 8; ++n) {
                int col = wc + n * 16 + l15;
                int grp = col >> 5, colw = col & 31;
                y2[((size_t)grp * NNP + row) * 32 + colw] = f2bf(acc[m][n][r] * nsv);
            }
        }
    }
}

// ------------------------------------------------- SpMM: branchless chains
__device__ inline void add8(float* a, uint4 v) {
    a[0] += __builtin_bit_cast(float, v.x << 16);
    a[1] += __builtin_bit_cast(float, v.x & 0xffff0000u);
    a[2] += __builtin_bit_cast(float, v.y << 16);
    a[3] += __builtin_bit_cast(float, v.y & 0xffff0000u);
    a[4] += __builtin_bit_cast(float, v.z << 16);
    a[5] += __builtin_bit_cast(float, v.z & 0xffff0000u);
    a[6] += __builtin_bit_cast(float, v.w << 16);
    a[7] += __builtin_bit_cast(float, v.w & 0xffff0000u);
}

__global__ __launch_bounds__(256) void k_spmm6(
        const ushort* __restrict__ y2, const int* __restrict__ off,
        const int* __restrict__ csr_src, const float* __restrict__ nd_arr,
        const float* __restrict__ bias, ushort* __restrict__ h_out) {
    __shared__ int sidx[4][SCAP];
    const int grp = blockIdx.x & 7;
    const int blk = blockIdx.x >> 3;          // 0..199
    const int tid = threadIdx.x;
    const int lane = tid & 63, wid = tid >> 6;
    const int slot = lane >> 2;               // 0..15
    const int sub = lane & 3;                 // 16B sub-chunk of the 32-col slice
    const ushort* ybase = y2 + (size_t)grp * NNP * 32 + sub * 8;

    const int nb = (blk * 4 + wid) * 64;
    int s_wave0 = 0, cnt = 0;
    if (nb < NN) {
        int nend = nb + 64 < NN ? nb + 64 : NN;
        s_wave0 = off[nb];
        cnt = off[nend] - s_wave0;
    }
    int stage = cnt < SCAP ? cnt : SCAP;
    for (int j = lane; j < stage; j += 64)
        sidx[wid][j] = csr_src[s_wave0 + j];
    __syncthreads();

    float bia[8];
    #pragma unroll
    for (int j = 0; j < 8; ++j) bia[j] = bias[grp * 32 + sub * 8 + j];

    int e0[4], e1[4];
    float a[4][8];
    #pragma unroll
    for (int c = 0; c < 4; ++c) {
        int n = nb + c * 16 + slot;
        bool v = n < NN;
        e0[c] = v ? off[n] - s_wave0 : 0;
        e1[c] = v ? off[n + 1] - s_wave0 : 0;
        #pragma unroll
        for (int j = 0; j < 8; ++j) a[c][j] = 0.f;
    }
    int tmax = max(max(e1[0] - e0[0], e1[1] - e0[1]), max(e1[2] - e0[2], e1[3] - e0[3]));

    if (cnt <= SCAP) {
        for (int t = 0; t < tmax; ++t) {
            uint4 v[4];
            #pragma unroll
            for (int c = 0; c < 4; ++c) {
                int ec = e0[c] + t;
                bool val = ec < e1[c];
                int ecc = val ? ec : 0;
                int id = sidx[wid][ecc];
                id = val ? id : ZROW;
                v[c] = *reinterpret_cast<const uint4*>(&ybase[(size_t)id * 32]);
            }
            #pragma unroll
            for (int c = 0; c < 4; ++c) add8(a[c], v[c]);
        }
    } else {
        for (int t = 0; t < tmax; ++t) {
            uint4 v[4];
            #pragma unroll
            for (int c = 0; c < 4; ++c) {
                int ec = e0[c] + t;
                bool val = ec < e1[c];
                int ecc = val ? ec : 0;
                int id = csr_src[s_wave0 + ecc];
                id = val ? id : ZROW;
                v[c] = *reinterpret_cast<const uint4*>(&ybase[(size_t)id * 32]);
            }
            #pragma unroll
            for (int c = 0; c < 4; ++c) add8(a[c], v[c]);
        }
    }

    #pragma unroll
    for (int c = 0; c < 4; ++c) {
        int n = nb + c * 16 + slot;
        if (n >= NN) continue;
        float nd = nd_arr[n];
        ushort r[8];
        #pragma unroll
        for (int j = 0; j < 8; ++j) r[j] = f2bf(fmaxf(a[c][j] * nd + bia[j], 0.f));
        uint4 pk;
        pk.x = (unsigned)r[0] | ((unsigned)r[1] << 16);
        pk.y = (unsigned)r[2] | ((unsigned)r[3] << 16);
        pk.z = (unsigned)r[4] | ((unsigned)r[5] << 16);
        pk.w = (unsigned)r[6] | ((unsigned)r[7] << 16);
        *reinterpret_cast<uint4*>(&h_out[(size_t)n * 256 + grp * 32 + sub * 8]) = pk;
    }
}

// ------------------------------------------------- MFMA tail: fc + dlog + losses
__global__ __launch_bounds__(256) void k_tail_mfma(
        const ushort* __restrict__ h0, const ushort* __restrict__ h1,
        const ushort* __restrict__ Wt1, const ushort* __restrict__ Wt2,
        const float* __restrict__ bfc, const float* __restrict__ bd,
        const int* __restrict__ labels, int g,
        float* __restrict__ pcls, float* __restrict__ pdom) {
    __shared__ float sT1[4][16][17];
    __shared__ float sT2[4][16][17];
    __shared__ float sc[4], sd[4];
    const int tid = threadIdx.x;
    const int wid = tid >> 6, lane = tid & 63;
    const int l15 = lane & 15, lg = lane >> 4;
    const int base = blockIdx.x * 64 + wid * 16;

    int arow = base + l15; if (arow >= NN) arow = NN - 1;
    const ushort* a1 = h1 + (size_t)arow * 256 + lg * 8;
    const ushort* a0 = h0 + (size_t)arow * 256 + lg * 8;
    const ushort* b1 = Wt1 + (size_t)l15 * 256 + lg * 8;
    const ushort* b2 = Wt2 + (size_t)l15 * 256 + lg * 8;
    f32x4 acc1 = {0.f, 0.f, 0.f, 0.f};
    f32x4 acc2 = {0.f, 0.f, 0.f, 0.f};
    #pragma unroll
    for (int kk = 0; kk < 8; ++kk) {
        bfrag af1 = *reinterpret_cast<const bfrag*>(a1 + kk * 32);
        bfrag bg1 = *reinterpret_cast<const bfrag*>(b1 + kk * 32);
        acc1 = __builtin_amdgcn_mfma_f32_16x16x32_bf16(af1, bg1, acc1, 0, 0, 0);
        bfrag af0 = *reinterpret_cast<const bfrag*>(a0 + kk * 32);
        bfrag bg2 = *reinterpret_cast<const bfrag*>(b2 + kk * 32);
        acc2 = __builtin_amdgcn_mfma_f32_16x16x32_bf16(af0, bg2, acc2, 0, 0, 0);
    }
    #pragma unroll
    for (int j = 0; j < 4; ++j) {
        sT1[wid][lg * 4 + j][l15] = acc1[j];
        sT2[wid][lg * 4 + j][l15] = acc2[j];
    }
    __syncthreads();

    float cls = 0.f, dom = 0.f;
    int n = base + lane;
    if (lane < 16 && n < NN) {
        float lgt[10];
        #pragma unroll
        for (int c = 0; c < 10; ++c) lgt[c] = sT1[wid][lane][c] + bfc[c];
        float dl0 = bd[0] + sT2[wid][lane][0] + sT1[wid][lane][10];
        float dl1 = bd[1] + sT2[wid][lane][1] + sT1[wid][lane][11];
        if (g == 0) {
            float m = lgt[0];
            #pragma unroll
            for (int c = 1; c < 10; ++c) m = fmaxf(m, lgt[c]);
            float s = 0.f;
            #pragma unroll
            for (int c = 0; c < 10; ++c) s += expf(lgt[c] - m);
            int lab = labels[n];
            float tgt = lgt[0];
            #pragma unroll
            for (int c = 1; c < 10; ++c) tgt = (c == lab) ? lgt[c] : tgt;
            cls = -(tgt - (m + logf(s)));
        }
        float m2 = fmaxf(dl0, dl1);
        float lse2 = m2 + logf(expf(dl0 - m2) + expf(dl1 - m2));
        dom = -((g ? dl1 : dl0) - lse2);
    }
    #pragma unroll
    for (int o = 1; o < 16; o <<= 1) {
        cls += __shfl_xor(cls, o, 64);
        dom += __shfl_xor(dom, o, 64);
    }
    if (lane == 0) { sc[wid] = cls; sd[wid] = dom; }
    __syncthreads();
    if (tid == 0) {
        float c = sc[0] + sc[1] + sc[2] + sc[3];
        float d = sd[0] + sd[1] + sd[2] + sd[3];
        if (g == 0) pcls[blockIdx.x] = c;
        pdom[g * NTB + blockIdx.x] = d;
    }
}

__global__ void k_finalize(const float* __restrict__ pcls, const float* __restrict__ pdom,
                           float* __restrict__ out) {
    __shared__ float sc[4], sd[4];
    int tid = threadIdx.x, lane = tid & 63, wid = tid >> 6;
    float c = 0.f, d = 0.f;
    for (int i = tid; i < NTB; i += 256) c += pcls[i];
    for (int i = tid; i < 2 * NTB; i += 256) d += pdom[i];
    #pragma unroll
    for (int o = 32; o; o >>= 1) {
        c += __shfl_xor(c, o, 64);
        d += __shfl_xor(d, o, 64);
    }
    if (lane == 0) { sc[wid] = c; sd[wid] = d; }
    __syncthreads();
    if (tid == 0) {
        float ct = sc[0] + sc[1] + sc[2] + sc[3];
        float dt = sd[0] + sd[1] + sd[2] + sd[3];
        out[0] = ct / (float)NN + 0.01f * (dt / (float)(2 * NN));
    }
}

// ---------------------------------------------------------------- launch
extern "C" void kernel_launch(void* const* d_in, const int* in_sizes, int n_in,
                              void* d_out, int out_size, void* d_ws, size_t ws_size,
                              hipStream_t stream) {
    const float* features_s = (const float*)d_in[0];
    const int*   labels_s   = (const int*)d_in[1];
    const float* features_t = (const float*)d_in[2];
    const int*   src_s      = (const int*)d_in[3];
    const int*   dst_s      = (const int*)d_in[4];
    const int*   src_t      = (const int*)d_in[5];
    const int*   dst_t      = (const int*)d_in[6];
    const float* W0         = (const float*)d_in[7];
    const float* b0         = (const float*)d_in[8];
    const float* W1         = (const float*)d_in[9];
    const float* b1         = (const float*)d_in[10];
    const float* Wfc        = (const float*)d_in[11];
    const float* bfc        = (const float*)d_in[12];
    const float* Wd         = (const float*)d_in[13];
    const float* bd         = (const float*)d_in[14];
    float* out = (float*)d_out;

    auto align256 = [](size_t x) { return (x + 255) & ~(size_t)255; };
    char* w = (char*)d_ws;
    ushort* h0     = (ushort*)w; w += align256((size_t)NN * HH * 2);     // 25.6 MB
    ushort* h1     = (ushort*)w; w += align256((size_t)NN * HH * 2);     // 25.6 MB
    ushort* y2     = (ushort*)w; w += align256((size_t)NNP * HH * 2);    // 25.6 MB grouped
    ushort* W0t    = (ushort*)w; w += align256((size_t)INF * HH * 2);
    ushort* W1t    = (ushort*)w; w += align256((size_t)HH * HH * 2);
    ushort* Wt1    = (ushort*)w; w += align256((size_t)16 * HH * 2);
    ushort* Wt2    = (ushort*)w; w += align256((size_t)16 * HH * 2);
    float* ns      = (float*)w;  w += align256((size_t)2 * NN * 4);
    float* nd      = (float*)w;  w += align256((size_t)2 * NN * 4);
    int*   cnt     = (int*)w;    w += align256((size_t)4 * NN * 4);
    int*   csr_off = (int*)w;    w += align256((size_t)(2 * NN + 1) * 4);
    int*   csr_src = (int*)w;    w += align256((size_t)2 * EE * 4);      // 6.4 MB
    int*   btot    = (int*)w;    w += align256((size_t)NB2 * 4);
    int*   bbase   = (int*)w;    w += align256((size_t)NB2 * 4);
    float* pcls    = (float*)w;  w += align256((size_t)NTB * 4);
    float* pdom    = (float*)w;  w += align256((size_t)2 * NTB * 4);
    ushort* pcnt   = (ushort*)w; w += align256((size_t)4 * HRNG * HSUB * HBIN * 2); // 12.8 MB
    int*   base2   = (int*)w;    w += align256((size_t)2 * HRNG * HSUB * HBIN * 4); // 12.8 MB

    const int TB = 256;
    k_cast_wt<INF><<<(INF * HH + TB - 1) / TB, TB, 0, stream>>>(W0, W0t);
    k_cast_wt<HH><<<(HH * HH + TB - 1) / TB, TB, 0, stream>>>(W1, W1t);
    k_cast_wtail<<<(16 * HH + TB - 1) / TB, TB, 0, stream>>>(Wfc, Wd, Wt1);
    k_cast_wtail2<<<(16 * HH + TB - 1) / TB, TB, 0, stream>>>(Wd, Wt2);

    // batched CSR prep (no global atomics anywhere)
    k_deghist<<<4 * HRNG * HSUB, TB, 0, stream>>>(src_s, dst_s, src_t, dst_t, pcnt);
    k_degsum<<<(4 * NN + TB - 1) / TB, TB, 0, stream>>>(pcnt, cnt);
    k_scan_blk<<<NB2, TB, 0, stream>>>(cnt, csr_off, btot);
    k_scan_tops<<<1, 512, 0, stream>>>(btot, bbase, csr_off);
    k_scan_fin<<<NB2, TB, 0, stream>>>(csr_off, bbase, cnt, ns, nd, y2);
    k_degpos<<<NB2, TB, 0, stream>>>(pcnt, csr_off, base2);
    k_fill3<<<16 * HSUB, TB, 0, stream>>>(src_s, dst_s, src_t, dst_t, base2, csr_src);

    const int GB = (NN + 127) / 128;   // 391
    for (int g = 0; g < 2; ++g) {
        const float* feats = g ? features_t : features_s;
        const int*   offg  = csr_off + (size_t)g * NN;
        const float* nsg   = ns + (size_t)g * NN;
        const float* ndg   = nd + (size_t)g * NN;

        k_gemm<INF, true><<<GB, TB, 0, stream>>>(feats, W0t, nsg, y2);
        k_spmm6<<<SPMM_BLOCKS, TB, 0, stream>>>(y2, offg, csr_src, ndg, b0, h0);
        k_gemm<HH, false><<<GB, TB, 0, stream>>>(h0, W1t, nsg, y2);
        k_spmm6<<<SPMM_BLOCKS, TB, 0, stream>>>(y2, offg, csr_src, ndg, b1, h1);
        k_tail_mfma<<<NTB, TB, 0, stream>>>(h0, h1, Wt1, Wt2, bfc, bd, labels_s, g,
                                            pcls, pdom);
    }
    k_finalize<<<1, TB, 0, stream>>>(pcls, pdom, out);
}